// Round 4
// baseline (914.531 us; speedup 1.0000x reference)
//
#include <hip/hip_runtime.h>
#include <math.h>

typedef unsigned short u16;
typedef unsigned int u32;
typedef float f32x4 __attribute__((ext_vector_type(4)));
typedef __bf16 bf16x8 __attribute__((ext_vector_type(8)));
typedef u16 us8 __attribute__((ext_vector_type(8)));
typedef u16 us4 __attribute__((ext_vector_type(4)));

#define MFMA_BF16 __builtin_amdgcn_mfma_f32_16x16x32_bf16

__device__ __forceinline__ u16 f2bf(float x){
  u32 u = __float_as_uint(x);
  u32 r = u + 0x7FFFu + ((u >> 16) & 1u);
  return (u16)(r >> 16);
}
__device__ __forceinline__ float bf2f(u16 h){ return __uint_as_float(((u32)h) << 16); }

// async global->LDS, 16B per lane; lds base must be wave-uniform (HW scatters lane*16)
__device__ __forceinline__ void gld16(u16* lds, const char* g){
  __builtin_amdgcn_global_load_lds((const __attribute__((address_space(1))) void*)g,
                                   (__attribute__((address_space(3))) void*)lds,
                                   16, 0, 0);
}

// ---------------------------------------------------------------- split weights
__global__ __launch_bounds__(256) void k_split_w(const float* __restrict__ Wq,
                                                 const float* __restrict__ Wk,
                                                 const float* __restrict__ Wv,
                                                 u16* __restrict__ whi, u16* __restrict__ wlo){
  const int z = blockIdx.y;
  const float* W = (z == 0) ? Wq : (z == 1) ? Wk : Wv;
  u16* hi = whi + (size_t)z * 1048576u;
  u16* lo = wlo + (size_t)z * 1048576u;
  const int i = (blockIdx.x * 256 + threadIdx.x) * 4;
  f32x4 v = *(const f32x4*)(W + i);
  u16 h[4], l[4];
  #pragma unroll
  for (int j = 0; j < 4; j++){
    h[j] = f2bf(v[j]);
    l[j] = f2bf(v[j] - bf2f(h[j]));
  }
  *(us4*)&hi[i] = *(const us4*)&h[0];
  *(us4*)&lo[i] = *(const us4*)&l[0];
}

// ---------------------------------------------------------------- split H
__global__ __launch_bounds__(256) void k_split_h(const float* __restrict__ H,
                                                 u16* __restrict__ Hhi, u16* __restrict__ Hlo){
  const size_t row = blockIdx.x;
  const int i = threadIdx.x * 4;
  f32x4 v = *(const f32x4*)(H + row * 1024 + i);
  u16 h[4], l[4];
  #pragma unroll
  for (int j = 0; j < 4; j++){
    h[j] = f2bf(v[j]);
    l[j] = f2bf(v[j] - bf2f(h[j]));
  }
  *(us4*)&Hhi[row * 1024 + i] = *(const us4*)&h[0];
  *(us4*)&Hlo[row * 1024 + i] = *(const us4*)&l[0];
}

// ---------------------------------------------------------------- Q+K projection GEMM (merged, 3-pass each)
// A (H hi/lo) staged ONCE per K-step, reused for both Q and K: 96 MFMA per wave-K-step.
__global__ __launch_bounds__(256) void k_projqk(
    const u16* __restrict__ Hhi, const u16* __restrict__ Hlo,
    const u16* __restrict__ Whi, const u16* __restrict__ Wlo,
    u16* __restrict__ Qhi, u16* __restrict__ Qlo,
    u16* __restrict__ Khi, u16* __restrict__ Klo)
{
  __shared__ __align__(16) u16 sAh[128*32];
  __shared__ __align__(16) u16 sAl[128*32];
  __shared__ __align__(16) u16 sBqh[128*32];
  __shared__ __align__(16) u16 sBql[128*32];
  __shared__ __align__(16) u16 sBkh[128*32];
  __shared__ __align__(16) u16 sBkl[128*32];
  const int tid = threadIdx.x, lane = tid & 63, w = tid >> 6;
  const int m0 = blockIdx.x * 128, n0 = blockIdx.y * 128;

  const int sr  = w * 32 + (lane >> 2);
  const int cb  = (lane & 3) * 16;
  const size_t aoff0 = (size_t)min(m0 + sr,      16399) * 2048 + cb;
  const size_t aoff1 = (size_t)min(m0 + sr + 16, 16399) * 2048 + cb;
  const size_t boff0 = (size_t)(n0 + sr)      * 2048 + cb;
  const size_t boff1 = (size_t)(n0 + sr + 16) * 2048 + cb;
  const char* Ah  = (const char*)Hhi;
  const char* Al  = (const char*)Hlo;
  const char* Bqh = (const char*)Whi;                  // Wq hi (z=0 plane)
  const char* Bql = (const char*)Wlo;
  const char* Bkh = (const char*)(Whi + 1048576u);     // Wk hi (z=1 plane)
  const char* Bkl = (const char*)(Wlo + 1048576u);

  const int wr = w >> 1, wc = w & 1;
  const int lrow = lane & 15;
  const int fo = (lane >> 4) * 8;

  f32x4 accq[4][4] = {};
  f32x4 acck[4][4] = {};

  for (int k0 = 0; k0 < 1024; k0 += 32){
    const size_t kb = (size_t)k0 * 2;
    gld16(sAh  + w*1024,       Ah  + aoff0 + kb);
    gld16(sAh  + w*1024 + 512, Ah  + aoff1 + kb);
    gld16(sAl  + w*1024,       Al  + aoff0 + kb);
    gld16(sAl  + w*1024 + 512, Al  + aoff1 + kb);
    gld16(sBqh + w*1024,       Bqh + boff0 + kb);
    gld16(sBqh + w*1024 + 512, Bqh + boff1 + kb);
    gld16(sBql + w*1024,       Bql + boff0 + kb);
    gld16(sBql + w*1024 + 512, Bql + boff1 + kb);
    gld16(sBkh + w*1024,       Bkh + boff0 + kb);
    gld16(sBkh + w*1024 + 512, Bkh + boff1 + kb);
    gld16(sBkl + w*1024,       Bkl + boff0 + kb);
    gld16(sBkl + w*1024 + 512, Bkl + boff1 + kb);
    __syncthreads();
    bf16x8 ah[4], al[4];
    #pragma unroll
    for (int m = 0; m < 4; m++){
      ah[m] = *(const bf16x8*)&sAh[(wr*64 + m*16 + lrow)*32 + fo];
      al[m] = *(const bf16x8*)&sAl[(wr*64 + m*16 + lrow)*32 + fo];
    }
    {
      bf16x8 bh[4], bl[4];
      #pragma unroll
      for (int n = 0; n < 4; n++){
        bh[n] = *(const bf16x8*)&sBqh[(wc*64 + n*16 + lrow)*32 + fo];
        bl[n] = *(const bf16x8*)&sBql[(wc*64 + n*16 + lrow)*32 + fo];
      }
      #pragma unroll
      for (int m = 0; m < 4; m++){
        #pragma unroll
        for (int n = 0; n < 4; n++){
          accq[m][n] = MFMA_BF16(ah[m], bh[n], accq[m][n], 0, 0, 0);
          accq[m][n] = MFMA_BF16(ah[m], bl[n], accq[m][n], 0, 0, 0);
          accq[m][n] = MFMA_BF16(al[m], bh[n], accq[m][n], 0, 0, 0);
        }
      }
    }
    {
      bf16x8 bh[4], bl[4];
      #pragma unroll
      for (int n = 0; n < 4; n++){
        bh[n] = *(const bf16x8*)&sBkh[(wc*64 + n*16 + lrow)*32 + fo];
        bl[n] = *(const bf16x8*)&sBkl[(wc*64 + n*16 + lrow)*32 + fo];
      }
      #pragma unroll
      for (int m = 0; m < 4; m++){
        #pragma unroll
        for (int n = 0; n < 4; n++){
          acck[m][n] = MFMA_BF16(ah[m], bh[n], acck[m][n], 0, 0, 0);
          acck[m][n] = MFMA_BF16(ah[m], bl[n], acck[m][n], 0, 0, 0);
          acck[m][n] = MFMA_BF16(al[m], bh[n], acck[m][n], 0, 0, 0);
        }
      }
    }
    __syncthreads();
  }
  const int r4 = (lane >> 4) * 4;
  #pragma unroll
  for (int m = 0; m < 4; m++){
    #pragma unroll
    for (int n = 0; n < 4; n++){
      #pragma unroll
      for (int j = 0; j < 4; j++){
        const int row = m0 + wr*64 + m*16 + r4 + j;
        const int col = n0 + wc*64 + n*16 + lrow;
        if (row < 16400){
          const size_t o = (size_t)row * 1024 + col;
          const float vq = accq[m][n][j];
          u16 hq = f2bf(vq); Qhi[o] = hq; Qlo[o] = f2bf(vq - bf2f(hq));
          const float vk = acck[m][n][j];
          u16 hk = f2bf(vk); Khi[o] = hk; Klo[o] = f2bf(vk - bf2f(hk));
        }
      }
    }
  }
}

// ---------------------------------------------------------------- V projection GEMM (1-pass)
__global__ __launch_bounds__(256) void k_projv(
    const u16* __restrict__ Hhi, const u16* __restrict__ Whi,
    u16* __restrict__ Vhi)
{
  __shared__ __align__(16) u16 sA[128*32];
  __shared__ __align__(16) u16 sB[128*32];
  const int tid = threadIdx.x, lane = tid & 63, w = tid >> 6;
  const int m0 = blockIdx.x * 128, n0 = blockIdx.y * 128;

  const int sr  = w * 32 + (lane >> 2);
  const int cb  = (lane & 3) * 16;
  const size_t aoff0 = (size_t)min(m0 + sr,      16399) * 2048 + cb;
  const size_t aoff1 = (size_t)min(m0 + sr + 16, 16399) * 2048 + cb;
  const size_t boff0 = (size_t)(n0 + sr)      * 2048 + cb;
  const size_t boff1 = (size_t)(n0 + sr + 16) * 2048 + cb;
  const char* Ah = (const char*)Hhi;
  const char* Bh = (const char*)(Whi + 2097152u);      // Wv hi (z=2 plane)

  const int wr = w >> 1, wc = w & 1;
  const int lrow = lane & 15;
  const int fo = (lane >> 4) * 8;

  f32x4 acc[4][4] = {};

  for (int k0 = 0; k0 < 1024; k0 += 32){
    const size_t kb = (size_t)k0 * 2;
    gld16(sA + w*1024,       Ah + aoff0 + kb);
    gld16(sA + w*1024 + 512, Ah + aoff1 + kb);
    gld16(sB + w*1024,       Bh + boff0 + kb);
    gld16(sB + w*1024 + 512, Bh + boff1 + kb);
    __syncthreads();
    bf16x8 a[4], bb[4];
    #pragma unroll
    for (int m = 0; m < 4; m++) a[m]  = *(const bf16x8*)&sA[(wr*64 + m*16 + lrow)*32 + fo];
    #pragma unroll
    for (int n = 0; n < 4; n++) bb[n] = *(const bf16x8*)&sB[(wc*64 + n*16 + lrow)*32 + fo];
    #pragma unroll
    for (int m = 0; m < 4; m++){
      #pragma unroll
      for (int n = 0; n < 4; n++){
        acc[m][n] = MFMA_BF16(a[m], bb[n], acc[m][n], 0, 0, 0);
      }
    }
    __syncthreads();
  }
  const int r4 = (lane >> 4) * 4;
  #pragma unroll
  for (int m = 0; m < 4; m++){
    #pragma unroll
    for (int n = 0; n < 4; n++){
      #pragma unroll
      for (int j = 0; j < 4; j++){
        const int row = m0 + wr*64 + m*16 + r4 + j;
        const int col = n0 + wc*64 + n*16 + lrow;
        if (row < 16400){
          Vhi[(size_t)row * 1024 + col] = f2bf(acc[m][n][j]);
        }
      }
    }
  }
}

// ---------------------------------------------------------------- scores GEMM (+bias)
__global__ __launch_bounds__(256) void k_scores(
    const u16* __restrict__ Qhi, const u16* __restrict__ Qlo,
    const u16* __restrict__ Khi, const u16* __restrict__ Klo,
    const float* __restrict__ bias_table, float* __restrict__ scores)
{
  __shared__ __align__(16) u16 sAh[128*32];
  __shared__ __align__(16) u16 sAl[128*32];
  __shared__ __align__(16) u16 sBh[128*32];
  __shared__ __align__(16) u16 sBl[128*32];
  const int tid = threadIdx.x, lane = tid & 63, w = tid >> 6;
  const int b  = blockIdx.z;
  const int m0 = blockIdx.x * 128, n0 = blockIdx.y * 128;

  const int sr = w * 32 + (lane >> 2);
  const int cb = (lane & 3) * 16;
  const size_t aoff0 = ((size_t)b*1025 + min(m0 + sr,      1024)) * 2048 + cb;
  const size_t aoff1 = ((size_t)b*1025 + min(m0 + sr + 16, 1024)) * 2048 + cb;
  const size_t boff0 = ((size_t)b*1025 + min(n0 + sr,      1024)) * 2048 + cb;
  const size_t boff1 = ((size_t)b*1025 + min(n0 + sr + 16, 1024)) * 2048 + cb;
  const char* Ah = (const char*)Qhi;
  const char* Al = (const char*)Qlo;
  const char* Bh = (const char*)Khi;
  const char* Bl = (const char*)Klo;

  const int wr = w >> 1, wc = w & 1;
  const int lrow = lane & 15;
  const int fo = (lane >> 4) * 8;

  f32x4 acc[4][4] = {};

  for (int k0 = 0; k0 < 1024; k0 += 32){
    const size_t kb = (size_t)k0 * 2;
    gld16(sAh + w*1024,       Ah + aoff0 + kb);
    gld16(sAh + w*1024 + 512, Ah + aoff1 + kb);
    gld16(sAl + w*1024,       Al + aoff0 + kb);
    gld16(sAl + w*1024 + 512, Al + aoff1 + kb);
    gld16(sBh + w*1024,       Bh + boff0 + kb);
    gld16(sBh + w*1024 + 512, Bh + boff1 + kb);
    gld16(sBl + w*1024,       Bl + boff0 + kb);
    gld16(sBl + w*1024 + 512, Bl + boff1 + kb);
    __syncthreads();
    bf16x8 ah[4], al[4], bh[4], bl[4];
    #pragma unroll
    for (int m = 0; m < 4; m++){
      ah[m] = *(const bf16x8*)&sAh[(wr*64 + m*16 + lrow)*32 + fo];
      al[m] = *(const bf16x8*)&sAl[(wr*64 + m*16 + lrow)*32 + fo];
    }
    #pragma unroll
    for (int n = 0; n < 4; n++){
      bh[n] = *(const bf16x8*)&sBh[(wc*64 + n*16 + lrow)*32 + fo];
      bl[n] = *(const bf16x8*)&sBl[(wc*64 + n*16 + lrow)*32 + fo];
    }
    #pragma unroll
    for (int m = 0; m < 4; m++){
      #pragma unroll
      for (int n = 0; n < 4; n++){
        acc[m][n] = MFMA_BF16(ah[m], bh[n], acc[m][n], 0, 0, 0);
        acc[m][n] = MFMA_BF16(ah[m], bl[n], acc[m][n], 0, 0, 0);
        acc[m][n] = MFMA_BF16(al[m], bh[n], acc[m][n], 0, 0, 0);
      }
    }
    __syncthreads();
  }
  const int r4 = (lane >> 4) * 4;
  #pragma unroll
  for (int m = 0; m < 4; m++){
    #pragma unroll
    for (int n = 0; n < 4; n++){
      #pragma unroll
      for (int j = 0; j < 4; j++){
        const int q  = m0 + wr*64 + m*16 + r4 + j;
        const int kk = n0 + wc*64 + n*16 + lrow;
        if (q < 1025 && kk < 1025){
          float v = acc[m][n][j];
          if (q > 0 && kk > 0){
            const int i = q - 1, jj = kk - 1;
            const int yi = i >> 5, xi = i & 31;
            const int yj = jj >> 5, xj = jj & 31;
            const int idx = (yi - yj + 31) * 63 + (xi - xj + 31);
            v += bias_table[idx * 16 + b];
          }
          scores[((size_t)b * 1025 + q) * 1028 + kk] = v;
        }
      }
    }
  }
}

// ---------------------------------------------------------------- V transpose  (Vt stride 1056, pad cols zeroed)
__global__ __launch_bounds__(256) void k_transpose_v(const u16* __restrict__ Vhi,
                                                     u16* __restrict__ Vt){
  __shared__ u16 T[32][33];
  const int b = blockIdx.z, s0 = blockIdx.x * 32, e0 = blockIdx.y * 32;
  const int tx = threadIdx.x & 31, ty = threadIdx.x >> 5;
  #pragma unroll
  for (int i = 0; i < 4; i++){
    const int s = s0 + ty + i * 8;
    T[ty + i*8][tx] = (s < 1025) ? Vhi[((size_t)b * 1025 + s) * 1024 + e0 + tx] : (u16)0;
  }
  __syncthreads();
  #pragma unroll
  for (int i = 0; i < 4; i++){
    const int e = e0 + ty + i * 8;
    const int s = s0 + tx;
    Vt[((size_t)b * 1024 + e) * 1056 + s] = T[tx][ty + i*8];
  }
}

// ---------------------------------------------------------------- softmax  (P stride 1056, pad cols zeroed)
__global__ __launch_bounds__(256) void k_softmax(const float* __restrict__ scores,
                                                 u16* __restrict__ P){
  __shared__ float red[4];
  const int tid = threadIdx.x;
  const size_t R = blockIdx.x;
  const float* __restrict__ row = scores + R * 1028;
  f32x4 v = *(const f32x4*)&row[tid * 4];
  const float extra = (tid == 0) ? row[1024] : -1e30f;
  float mx = fmaxf(fmaxf(v[0], v[1]), fmaxf(v[2], v[3]));
  mx = fmaxf(mx, extra);
  #pragma unroll
  for (int off = 32; off >= 1; off >>= 1) mx = fmaxf(mx, __shfl_down(mx, off, 64));
  if ((tid & 63) == 0) red[tid >> 6] = mx;
  __syncthreads();
  mx = fmaxf(fmaxf(red[0], red[1]), fmaxf(red[2], red[3]));
  __syncthreads();
  f32x4 e;
  e[0] = __expf(v[0] - mx); e[1] = __expf(v[1] - mx);
  e[2] = __expf(v[2] - mx); e[3] = __expf(v[3] - mx);
  const float e4 = (tid == 0) ? __expf(extra - mx) : 0.f;
  float s = e[0] + e[1] + e[2] + e[3] + e4;
  #pragma unroll
  for (int off = 32; off >= 1; off >>= 1) s += __shfl_down(s, off, 64);
  if ((tid & 63) == 0) red[tid >> 6] = s;
  __syncthreads();
  s = red[0] + red[1] + red[2] + red[3];
  const float inv = 1.0f / s;
  u16 p[4];
  p[0] = f2bf(e[0] * inv); p[1] = f2bf(e[1] * inv);
  p[2] = f2bf(e[2] * inv); p[3] = f2bf(e[3] * inv);
  *(us4*)&P[R * 1056 + tid * 4] = *(const us4*)&p[0];
  if (tid < 32){
    P[R * 1056 + 1024 + tid] = (tid == 0) ? f2bf(e4 * inv) : (u16)0;
  }
}

// ---------------------------------------------------------------- PV GEMM
__global__ __launch_bounds__(256) void k_pv(const u16* __restrict__ P,
                                            const u16* __restrict__ Vt,
                                            float* __restrict__ out)
{
  __shared__ __align__(16) u16 sA[128*32];
  __shared__ __align__(16) u16 sB[128*32];
  const int tid = threadIdx.x, lane = tid & 63, w = tid >> 6;
  const int b  = blockIdx.z;
  const int m0 = blockIdx.x * 128, n0 = blockIdx.y * 128;

  const int sr = w * 32 + (lane >> 2);
  const int cb = (lane & 3) * 16;
  const size_t aoff0 = ((size_t)b*1025 + min(m0 + sr,      1024)) * 2112 + cb;
  const size_t aoff1 = ((size_t)b*1025 + min(m0 + sr + 16, 1024)) * 2112 + cb;
  const size_t boff0 = ((size_t)b*1024 + n0 + sr)      * 2112 + cb;
  const size_t boff1 = ((size_t)b*1024 + n0 + sr + 16) * 2112 + cb;
  const char* Ap = (const char*)P;
  const char* Bp = (const char*)Vt;

  const int wr = w >> 1, wc = w & 1;
  const int lrow = lane & 15;
  const int fo = (lane >> 4) * 8;

  f32x4 acc[4][4] = {};

  for (int k0 = 0; k0 < 1056; k0 += 32){
    const size_t kb = (size_t)k0 * 2;
    gld16(sA + w*1024,       Ap + aoff0 + kb);
    gld16(sA + w*1024 + 512, Ap + aoff1 + kb);
    gld16(sB + w*1024,       Bp + boff0 + kb);
    gld16(sB + w*1024 + 512, Bp + boff1 + kb);
    __syncthreads();
    bf16x8 a[4], bb[4];
    #pragma unroll
    for (int m = 0; m < 4; m++)
      a[m] = *(const bf16x8*)&sA[(wr*64 + m*16 + lrow)*32 + fo];
    #pragma unroll
    for (int n = 0; n < 4; n++)
      bb[n] = *(const bf16x8*)&sB[(wc*64 + n*16 + lrow)*32 + fo];
    #pragma unroll
    for (int m = 0; m < 4; m++){
      #pragma unroll
      for (int n = 0; n < 4; n++){
        acc[m][n] = MFMA_BF16(a[m], bb[n], acc[m][n], 0, 0, 0);
      }
    }
    __syncthreads();
  }
  const int r4 = (lane >> 4) * 4;
  #pragma unroll
  for (int m = 0; m < 4; m++){
    #pragma unroll
    for (int n = 0; n < 4; n++){
      #pragma unroll
      for (int j = 0; j < 4; j++){
        const int q = m0 + wr*64 + m*16 + r4 + j;
        const int e = n0 + wc*64 + n*16 + lrow;
        if (q < 1025){
          out[((size_t)b * 1025 + q) * 1024 + e] = acc[m][n][j];
        }
      }
    }
  }
}

// ---------------------------------------------------------------- launch
extern "C" void kernel_launch(void* const* d_in, const int* in_sizes, int n_in,
                              void* d_out, int out_size, void* d_ws, size_t ws_size,
                              hipStream_t stream)
{
  const float* H          = (const float*)d_in[0];
  const float* Wq         = (const float*)d_in[1];
  const float* Wk         = (const float*)d_in[2];
  const float* Wv         = (const float*)d_in[3];
  const float* bias_table = (const float*)d_in[4];
  float* out = (float*)d_out;
  char* ws = (char*)d_ws;

  // workspace layout (bytes), peak 247,955,712:
  //  [0,          33,587,200) Hhi            -> later scores [0, 67,436,800)
  //  [33,587,200, 67,174,400) Hlo
  //  [67,436,800, 73,728,256) Whi            -> later Vt [67,436,800, 102,039,808)
  //  [73,728,256, 80,019,712) Wlo
  //  [80,019,712,113,606,912) Qhi
  //  [113,606,912,147,194,112) Qlo           -> later P [113,606,912, 148,243,712)
  //  [147,194,112,180,781,312) Khi
  //  [180,781,312,214,368,512) Klo
  //  [214,368,512,247,955,712) Vhi
  u16* Hhi = (u16*)(ws + 0);
  u16* Hlo = (u16*)(ws + 33587200ull);
  u16* Whi = (u16*)(ws + 67436800ull);
  u16* Wlo = (u16*)(ws + 73728256ull);
  u16* Qhi = (u16*)(ws + 80019712ull);
  u16* Qlo = (u16*)(ws + 113606912ull);
  u16* Khi = (u16*)(ws + 147194112ull);
  u16* Klo = (u16*)(ws + 180781312ull);
  u16* Vhi = (u16*)(ws + 214368512ull);
  float* scores = (float*)(ws + 0);
  u16* Vt = (u16*)(ws + 67436800ull);
  u16* P  = (u16*)(ws + 113606912ull);

  k_split_w    <<<dim3(1024, 3, 1),  256, 0, stream>>>(Wq, Wk, Wv, Whi, Wlo);
  k_split_h    <<<dim3(16400, 1, 1), 256, 0, stream>>>(H, Hhi, Hlo);
  k_projqk     <<<dim3(129, 8, 1),   256, 0, stream>>>(Hhi, Hlo, Whi, Wlo, Qhi, Qlo, Khi, Klo);
  k_projv      <<<dim3(129, 8, 1),   256, 0, stream>>>(Hhi, Whi, Vhi);
  k_scores     <<<dim3(9, 9, 16),    256, 0, stream>>>(Qhi, Qlo, Khi, Klo, bias_table, scores);
  k_transpose_v<<<dim3(33, 32, 16),  256, 0, stream>>>(Vhi, Vt);
  k_softmax    <<<dim3(16400, 1, 1), 256, 0, stream>>>(scores, P);
  k_pv         <<<dim3(9, 8, 16),    256, 0, stream>>>(P, Vt, out);
}

// Round 5
// 760.731 us; speedup vs baseline: 1.2022x; 1.2022x over previous
//
#include <hip/hip_runtime.h>
#include <math.h>

typedef unsigned short u16;
typedef unsigned int u32;
typedef float f32x4 __attribute__((ext_vector_type(4)));
typedef __bf16 bf16x8 __attribute__((ext_vector_type(8)));
typedef u16 us8 __attribute__((ext_vector_type(8)));
typedef u16 us4 __attribute__((ext_vector_type(4)));

#define MFMA_BF16 __builtin_amdgcn_mfma_f32_16x16x32_bf16

__device__ __forceinline__ u16 f2bf(float x){
  u32 u = __float_as_uint(x);
  u32 r = u + 0x7FFFu + ((u >> 16) & 1u);
  return (u16)(r >> 16);
}
__device__ __forceinline__ float bf2f(u16 h){ return __uint_as_float(((u32)h) << 16); }

// async global->LDS, 16B per lane; lds base must be wave-uniform (HW scatters lane*16)
__device__ __forceinline__ void gld16(u16* lds, const char* g){
  __builtin_amdgcn_global_load_lds((const __attribute__((address_space(1))) void*)g,
                                   (__attribute__((address_space(3))) void*)lds,
                                   16, 0, 0);
}

// ---------------------------------------------------------------- split(+transpose) weights
// z=0: Wq -> Wqt hi/lo (transposed). z=1: Wk -> Wkt hi/lo (transposed). z=2: Wv -> Wvh (plain, hi only).
__global__ __launch_bounds__(256) void k_split_wt(const float* __restrict__ Wq,
                                                  const float* __restrict__ Wk,
                                                  const float* __restrict__ Wv,
                                                  u16* __restrict__ Wqth, u16* __restrict__ Wqtl,
                                                  u16* __restrict__ Wkth, u16* __restrict__ Wktl,
                                                  u16* __restrict__ Wvh){
  const int z = blockIdx.z;
  const int r0 = blockIdx.y * 32, c0 = blockIdx.x * 32;
  const int tx = threadIdx.x & 31, ty = threadIdx.x >> 5;
  if (z == 2){
    #pragma unroll
    for (int i = 0; i < 4; i++){
      const int r = r0 + ty + i * 8;
      Wvh[(size_t)r * 1024 + c0 + tx] = f2bf(Wv[(size_t)r * 1024 + c0 + tx]);
    }
    return;
  }
  const float* __restrict__ W = (z == 0) ? Wq : Wk;
  u16* __restrict__ hi = (z == 0) ? Wqth : Wkth;
  u16* __restrict__ lo = (z == 0) ? Wqtl : Wktl;
  __shared__ float T[32][33];
  #pragma unroll
  for (int i = 0; i < 4; i++){
    T[ty + i*8][tx] = W[(size_t)(r0 + ty + i*8) * 1024 + c0 + tx];
  }
  __syncthreads();
  #pragma unroll
  for (int i = 0; i < 4; i++){
    const float v = T[tx][ty + i*8];
    const u16 h = f2bf(v);
    const size_t o = (size_t)(c0 + ty + i*8) * 1024 + r0 + tx;
    hi[o] = h;
    lo[o] = f2bf(v - bf2f(h));
  }
}

// ---------------------------------------------------------------- split H
__global__ __launch_bounds__(256) void k_split_h(const float* __restrict__ H,
                                                 u16* __restrict__ Hhi, u16* __restrict__ Hlo){
  const size_t row = blockIdx.x;
  const int i = threadIdx.x * 4;
  f32x4 v = *(const f32x4*)(H + row * 1024 + i);
  u16 h[4], l[4];
  #pragma unroll
  for (int j = 0; j < 4; j++){
    h[j] = f2bf(v[j]);
    l[j] = f2bf(v[j] - bf2f(h[j]));
  }
  *(us4*)&Hhi[row * 1024 + i] = *(const us4*)&h[0];
  *(us4*)&Hlo[row * 1024 + i] = *(const us4*)&l[0];
}

// ---------------------------------------------------------------- GT = pattern(Wkt, Wqt), 3-pass, split output
// GT[d',d] = sum_e Wkt[d',e]*Wqt[d,e]  (= Wk^T Wq reindexed so later GEMMs contract over last dim)
__global__ __launch_bounds__(256) void k_gt(
    const u16* __restrict__ Akth, const u16* __restrict__ Aktl,
    const u16* __restrict__ Bqth, const u16* __restrict__ Bqtl,
    u16* __restrict__ GThi, u16* __restrict__ GTlo)
{
  __shared__ __align__(16) u16 sAh[128*32];
  __shared__ __align__(16) u16 sAl[128*32];
  __shared__ __align__(16) u16 sBh[128*32];
  __shared__ __align__(16) u16 sBl[128*32];
  const int tid = threadIdx.x, lane = tid & 63, w = tid >> 6;
  const int m0 = blockIdx.x * 128, n0 = blockIdx.y * 128;

  const int sr = w * 32 + (lane >> 2);
  const int cb = (lane & 3) * 16;
  const size_t aoff0 = (size_t)(m0 + sr)      * 2048 + cb;
  const size_t aoff1 = (size_t)(m0 + sr + 16) * 2048 + cb;
  const size_t boff0 = (size_t)(n0 + sr)      * 2048 + cb;
  const size_t boff1 = (size_t)(n0 + sr + 16) * 2048 + cb;
  const char* Ah = (const char*)Akth;
  const char* Al = (const char*)Aktl;
  const char* Bh = (const char*)Bqth;
  const char* Bl = (const char*)Bqtl;

  const int wr = w >> 1, wc = w & 1;
  const int lrow = lane & 15;
  const int fo = (lane >> 4) * 8;

  f32x4 acc[4][4] = {};

  for (int k0 = 0; k0 < 1024; k0 += 32){
    const size_t kb = (size_t)k0 * 2;
    gld16(sAh + w*1024,       Ah + aoff0 + kb);
    gld16(sAh + w*1024 + 512, Ah + aoff1 + kb);
    gld16(sAl + w*1024,       Al + aoff0 + kb);
    gld16(sAl + w*1024 + 512, Al + aoff1 + kb);
    gld16(sBh + w*1024,       Bh + boff0 + kb);
    gld16(sBh + w*1024 + 512, Bh + boff1 + kb);
    gld16(sBl + w*1024,       Bl + boff0 + kb);
    gld16(sBl + w*1024 + 512, Bl + boff1 + kb);
    __syncthreads();
    bf16x8 ah[4], al[4], bh[4], bl[4];
    #pragma unroll
    for (int m = 0; m < 4; m++){
      ah[m] = *(const bf16x8*)&sAh[(wr*64 + m*16 + lrow)*32 + fo];
      al[m] = *(const bf16x8*)&sAl[(wr*64 + m*16 + lrow)*32 + fo];
    }
    #pragma unroll
    for (int n = 0; n < 4; n++){
      bh[n] = *(const bf16x8*)&sBh[(wc*64 + n*16 + lrow)*32 + fo];
      bl[n] = *(const bf16x8*)&sBl[(wc*64 + n*16 + lrow)*32 + fo];
    }
    #pragma unroll
    for (int m = 0; m < 4; m++){
      #pragma unroll
      for (int n = 0; n < 4; n++){
        acc[m][n] = MFMA_BF16(ah[m], bh[n], acc[m][n], 0, 0, 0);
        acc[m][n] = MFMA_BF16(ah[m], bl[n], acc[m][n], 0, 0, 0);
        acc[m][n] = MFMA_BF16(al[m], bh[n], acc[m][n], 0, 0, 0);
      }
    }
    __syncthreads();
  }
  const int r4 = (lane >> 4) * 4;
  #pragma unroll
  for (int m = 0; m < 4; m++){
    #pragma unroll
    for (int n = 0; n < 4; n++){
      #pragma unroll
      for (int j = 0; j < 4; j++){
        const int row = m0 + wr*64 + m*16 + r4 + j;
        const int col = n0 + wc*64 + n*16 + lrow;
        const float v = acc[m][n][j];
        const size_t o = (size_t)row * 1024 + col;
        const u16 h = f2bf(v);
        GThi[o] = h;
        GTlo[o] = f2bf(v - bf2f(h));
      }
    }
  }
}

// ---------------------------------------------------------------- HM = pattern(H, GT), 3-pass, split output
__global__ __launch_bounds__(256) void k_ghm(
    const u16* __restrict__ Hhi, const u16* __restrict__ Hlo,
    const u16* __restrict__ GThi, const u16* __restrict__ GTlo,
    u16* __restrict__ HMhi, u16* __restrict__ HMlo)
{
  __shared__ __align__(16) u16 sAh[128*32];
  __shared__ __align__(16) u16 sAl[128*32];
  __shared__ __align__(16) u16 sBh[128*32];
  __shared__ __align__(16) u16 sBl[128*32];
  const int tid = threadIdx.x, lane = tid & 63, w = tid >> 6;
  const int m0 = blockIdx.x * 128, n0 = blockIdx.y * 128;

  const int sr = w * 32 + (lane >> 2);
  const int cb = (lane & 3) * 16;
  const size_t aoff0 = (size_t)min(m0 + sr,      16399) * 2048 + cb;
  const size_t aoff1 = (size_t)min(m0 + sr + 16, 16399) * 2048 + cb;
  const size_t boff0 = (size_t)(n0 + sr)      * 2048 + cb;
  const size_t boff1 = (size_t)(n0 + sr + 16) * 2048 + cb;
  const char* Ah = (const char*)Hhi;
  const char* Al = (const char*)Hlo;
  const char* Bh = (const char*)GThi;
  const char* Bl = (const char*)GTlo;

  const int wr = w >> 1, wc = w & 1;
  const int lrow = lane & 15;
  const int fo = (lane >> 4) * 8;

  f32x4 acc[4][4] = {};

  for (int k0 = 0; k0 < 1024; k0 += 32){
    const size_t kb = (size_t)k0 * 2;
    gld16(sAh + w*1024,       Ah + aoff0 + kb);
    gld16(sAh + w*1024 + 512, Ah + aoff1 + kb);
    gld16(sAl + w*1024,       Al + aoff0 + kb);
    gld16(sAl + w*1024 + 512, Al + aoff1 + kb);
    gld16(sBh + w*1024,       Bh + boff0 + kb);
    gld16(sBh + w*1024 + 512, Bh + boff1 + kb);
    gld16(sBl + w*1024,       Bl + boff0 + kb);
    gld16(sBl + w*1024 + 512, Bl + boff1 + kb);
    __syncthreads();
    bf16x8 ah[4], al[4], bh[4], bl[4];
    #pragma unroll
    for (int m = 0; m < 4; m++){
      ah[m] = *(const bf16x8*)&sAh[(wr*64 + m*16 + lrow)*32 + fo];
      al[m] = *(const bf16x8*)&sAl[(wr*64 + m*16 + lrow)*32 + fo];
    }
    #pragma unroll
    for (int n = 0; n < 4; n++){
      bh[n] = *(const bf16x8*)&sBh[(wc*64 + n*16 + lrow)*32 + fo];
      bl[n] = *(const bf16x8*)&sBl[(wc*64 + n*16 + lrow)*32 + fo];
    }
    #pragma unroll
    for (int m = 0; m < 4; m++){
      #pragma unroll
      for (int n = 0; n < 4; n++){
        acc[m][n] = MFMA_BF16(ah[m], bh[n], acc[m][n], 0, 0, 0);
        acc[m][n] = MFMA_BF16(ah[m], bl[n], acc[m][n], 0, 0, 0);
        acc[m][n] = MFMA_BF16(al[m], bh[n], acc[m][n], 0, 0, 0);
      }
    }
    __syncthreads();
  }
  const int r4 = (lane >> 4) * 4;
  #pragma unroll
  for (int m = 0; m < 4; m++){
    #pragma unroll
    for (int n = 0; n < 4; n++){
      #pragma unroll
      for (int j = 0; j < 4; j++){
        const int row = m0 + wr*64 + m*16 + r4 + j;
        const int col = n0 + wc*64 + n*16 + lrow;
        if (row < 16400){
          const float v = acc[m][n][j];
          const size_t o = (size_t)row * 1024 + col;
          const u16 h = f2bf(v);
          HMhi[o] = h;
          HMlo[o] = f2bf(v - bf2f(h));
        }
      }
    }
  }
}

// ---------------------------------------------------------------- scores GEMM (+bias): scores = HM . H^T
__global__ __launch_bounds__(256) void k_scores(
    const u16* __restrict__ HMhi, const u16* __restrict__ HMlo,
    const u16* __restrict__ Hhi, const u16* __restrict__ Hlo,
    const float* __restrict__ bias_table, float* __restrict__ scores)
{
  __shared__ __align__(16) u16 sAh[128*32];
  __shared__ __align__(16) u16 sAl[128*32];
  __shared__ __align__(16) u16 sBh[128*32];
  __shared__ __align__(16) u16 sBl[128*32];
  const int tid = threadIdx.x, lane = tid & 63, w = tid >> 6;
  const int b  = blockIdx.z;
  const int m0 = blockIdx.x * 128, n0 = blockIdx.y * 128;

  const int sr = w * 32 + (lane >> 2);
  const int cb = (lane & 3) * 16;
  const size_t aoff0 = ((size_t)b*1025 + min(m0 + sr,      1024)) * 2048 + cb;
  const size_t aoff1 = ((size_t)b*1025 + min(m0 + sr + 16, 1024)) * 2048 + cb;
  const size_t boff0 = ((size_t)b*1025 + min(n0 + sr,      1024)) * 2048 + cb;
  const size_t boff1 = ((size_t)b*1025 + min(n0 + sr + 16, 1024)) * 2048 + cb;
  const char* Ah = (const char*)HMhi;
  const char* Al = (const char*)HMlo;
  const char* Bh = (const char*)Hhi;
  const char* Bl = (const char*)Hlo;

  const int wr = w >> 1, wc = w & 1;
  const int lrow = lane & 15;
  const int fo = (lane >> 4) * 8;

  f32x4 acc[4][4] = {};

  for (int k0 = 0; k0 < 1024; k0 += 32){
    const size_t kb = (size_t)k0 * 2;
    gld16(sAh + w*1024,       Ah + aoff0 + kb);
    gld16(sAh + w*1024 + 512, Ah + aoff1 + kb);
    gld16(sAl + w*1024,       Al + aoff0 + kb);
    gld16(sAl + w*1024 + 512, Al + aoff1 + kb);
    gld16(sBh + w*1024,       Bh + boff0 + kb);
    gld16(sBh + w*1024 + 512, Bh + boff1 + kb);
    gld16(sBl + w*1024,       Bl + boff0 + kb);
    gld16(sBl + w*1024 + 512, Bl + boff1 + kb);
    __syncthreads();
    bf16x8 ah[4], al[4], bh[4], bl[4];
    #pragma unroll
    for (int m = 0; m < 4; m++){
      ah[m] = *(const bf16x8*)&sAh[(wr*64 + m*16 + lrow)*32 + fo];
      al[m] = *(const bf16x8*)&sAl[(wr*64 + m*16 + lrow)*32 + fo];
    }
    #pragma unroll
    for (int n = 0; n < 4; n++){
      bh[n] = *(const bf16x8*)&sBh[(wc*64 + n*16 + lrow)*32 + fo];
      bl[n] = *(const bf16x8*)&sBl[(wc*64 + n*16 + lrow)*32 + fo];
    }
    #pragma unroll
    for (int m = 0; m < 4; m++){
      #pragma unroll
      for (int n = 0; n < 4; n++){
        acc[m][n] = MFMA_BF16(ah[m], bh[n], acc[m][n], 0, 0, 0);
        acc[m][n] = MFMA_BF16(ah[m], bl[n], acc[m][n], 0, 0, 0);
        acc[m][n] = MFMA_BF16(al[m], bh[n], acc[m][n], 0, 0, 0);
      }
    }
    __syncthreads();
  }
  const int r4 = (lane >> 4) * 4;
  #pragma unroll
  for (int m = 0; m < 4; m++){
    #pragma unroll
    for (int n = 0; n < 4; n++){
      #pragma unroll
      for (int j = 0; j < 4; j++){
        const int q  = m0 + wr*64 + m*16 + r4 + j;
        const int kk = n0 + wc*64 + n*16 + lrow;
        if (q < 1025 && kk < 1025){
          float v = acc[m][n][j];
          if (q > 0 && kk > 0){
            const int i = q - 1, jj = kk - 1;
            const int yi = i >> 5, xi = i & 31;
            const int yj = jj >> 5, xj = jj & 31;
            const int idx = (yi - yj + 31) * 63 + (xi - xj + 31);
            v += bias_table[idx * 16 + b];
          }
          scores[((size_t)b * 1025 + q) * 1028 + kk] = v;
        }
      }
    }
  }
}

// ---------------------------------------------------------------- V projection GEMM (1-pass)
__global__ __launch_bounds__(256) void k_projv(
    const u16* __restrict__ Hhi, const u16* __restrict__ Wvh,
    u16* __restrict__ Vhi)
{
  __shared__ __align__(16) u16 sA[128*32];
  __shared__ __align__(16) u16 sB[128*32];
  const int tid = threadIdx.x, lane = tid & 63, w = tid >> 6;
  const int m0 = blockIdx.x * 128, n0 = blockIdx.y * 128;

  const int sr  = w * 32 + (lane >> 2);
  const int cb  = (lane & 3) * 16;
  const size_t aoff0 = (size_t)min(m0 + sr,      16399) * 2048 + cb;
  const size_t aoff1 = (size_t)min(m0 + sr + 16, 16399) * 2048 + cb;
  const size_t boff0 = (size_t)(n0 + sr)      * 2048 + cb;
  const size_t boff1 = (size_t)(n0 + sr + 16) * 2048 + cb;
  const char* Ah = (const char*)Hhi;
  const char* Bh = (const char*)Wvh;

  const int wr = w >> 1, wc = w & 1;
  const int lrow = lane & 15;
  const int fo = (lane >> 4) * 8;

  f32x4 acc[4][4] = {};

  for (int k0 = 0; k0 < 1024; k0 += 32){
    const size_t kb = (size_t)k0 * 2;
    gld16(sA + w*1024,       Ah + aoff0 + kb);
    gld16(sA + w*1024 + 512, Ah + aoff1 + kb);
    gld16(sB + w*1024,       Bh + boff0 + kb);
    gld16(sB + w*1024 + 512, Bh + boff1 + kb);
    __syncthreads();
    bf16x8 a[4], bb[4];
    #pragma unroll
    for (int m = 0; m < 4; m++) a[m]  = *(const bf16x8*)&sA[(wr*64 + m*16 + lrow)*32 + fo];
    #pragma unroll
    for (int n = 0; n < 4; n++) bb[n] = *(const bf16x8*)&sB[(wc*64 + n*16 + lrow)*32 + fo];
    #pragma unroll
    for (int m = 0; m < 4; m++){
      #pragma unroll
      for (int n = 0; n < 4; n++){
        acc[m][n] = MFMA_BF16(a[m], bb[n], acc[m][n], 0, 0, 0);
      }
    }
    __syncthreads();
  }
  const int r4 = (lane >> 4) * 4;
  #pragma unroll
  for (int m = 0; m < 4; m++){
    #pragma unroll
    for (int n = 0; n < 4; n++){
      #pragma unroll
      for (int j = 0; j < 4; j++){
        const int row = m0 + wr*64 + m*16 + r4 + j;
        const int col = n0 + wc*64 + n*16 + lrow;
        if (row < 16400){
          Vhi[(size_t)row * 1024 + col] = f2bf(acc[m][n][j]);
        }
      }
    }
  }
}

// ---------------------------------------------------------------- V transpose  (Vt stride 1056, pad cols zeroed)
__global__ __launch_bounds__(256) void k_transpose_v(const u16* __restrict__ Vhi,
                                                     u16* __restrict__ Vt){
  __shared__ u16 T[32][33];
  const int b = blockIdx.z, s0 = blockIdx.x * 32, e0 = blockIdx.y * 32;
  const int tx = threadIdx.x & 31, ty = threadIdx.x >> 5;
  #pragma unroll
  for (int i = 0; i < 4; i++){
    const int s = s0 + ty + i * 8;
    T[ty + i*8][tx] = (s < 1025) ? Vhi[((size_t)b * 1025 + s) * 1024 + e0 + tx] : (u16)0;
  }
  __syncthreads();
  #pragma unroll
  for (int i = 0; i < 4; i++){
    const int e = e0 + ty + i * 8;
    const int s = s0 + tx;
    Vt[((size_t)b * 1024 + e) * 1056 + s] = T[tx][ty + i*8];
  }
}

// ---------------------------------------------------------------- softmax  (P stride 1056, pad cols zeroed)
__global__ __launch_bounds__(256) void k_softmax(const float* __restrict__ scores,
                                                 u16* __restrict__ P){
  __shared__ float red[4];
  const int tid = threadIdx.x;
  const size_t R = blockIdx.x;
  const float* __restrict__ row = scores + R * 1028;
  f32x4 v = *(const f32x4*)&row[tid * 4];
  const float extra = (tid == 0) ? row[1024] : -1e30f;
  float mx = fmaxf(fmaxf(v[0], v[1]), fmaxf(v[2], v[3]));
  mx = fmaxf(mx, extra);
  #pragma unroll
  for (int off = 32; off >= 1; off >>= 1) mx = fmaxf(mx, __shfl_down(mx, off, 64));
  if ((tid & 63) == 0) red[tid >> 6] = mx;
  __syncthreads();
  mx = fmaxf(fmaxf(red[0], red[1]), fmaxf(red[2], red[3]));
  __syncthreads();
  f32x4 e;
  e[0] = __expf(v[0] - mx); e[1] = __expf(v[1] - mx);
  e[2] = __expf(v[2] - mx); e[3] = __expf(v[3] - mx);
  const float e4 = (tid == 0) ? __expf(extra - mx) : 0.f;
  float s = e[0] + e[1] + e[2] + e[3] + e4;
  #pragma unroll
  for (int off = 32; off >= 1; off >>= 1) s += __shfl_down(s, off, 64);
  if ((tid & 63) == 0) red[tid >> 6] = s;
  __syncthreads();
  s = red[0] + red[1] + red[2] + red[3];
  const float inv = 1.0f / s;
  u16 p[4];
  p[0] = f2bf(e[0] * inv); p[1] = f2bf(e[1] * inv);
  p[2] = f2bf(e[2] * inv); p[3] = f2bf(e[3] * inv);
  *(us4*)&P[R * 1056 + tid * 4] = *(const us4*)&p[0];
  if (tid < 32){
    P[R * 1056 + 1024 + tid] = (tid == 0) ? f2bf(e4 * inv) : (u16)0;
  }
}

// ---------------------------------------------------------------- PV GEMM
__global__ __launch_bounds__(256) void k_pv(const u16* __restrict__ P,
                                            const u16* __restrict__ Vt,
                                            float* __restrict__ out)
{
  __shared__ __align__(16) u16 sA[128*32];
  __shared__ __align__(16) u16 sB[128*32];
  const int tid = threadIdx.x, lane = tid & 63, w = tid >> 6;
  const int b  = blockIdx.z;
  const int m0 = blockIdx.x * 128, n0 = blockIdx.y * 128;

  const int sr = w * 32 + (lane >> 2);
  const int cb = (lane & 3) * 16;
  const size_t aoff0 = ((size_t)b*1025 + min(m0 + sr,      1024)) * 2112 + cb;
  const size_t aoff1 = ((size_t)b*1025 + min(m0 + sr + 16, 1024)) * 2112 + cb;
  const size_t boff0 = ((size_t)b*1024 + n0 + sr)      * 2112 + cb;
  const size_t boff1 = ((size_t)b*1024 + n0 + sr + 16) * 2112 + cb;
  const char* Ap = (const char*)P;
  const char* Bp = (const char*)Vt;

  const int wr = w >> 1, wc = w & 1;
  const int lrow = lane & 15;
  const int fo = (lane >> 4) * 8;

  f32x4 acc[4][4] = {};

  for (int k0 = 0; k0 < 1056; k0 += 32){
    const size_t kb = (size_t)k0 * 2;
    gld16(sA + w*1024,       Ap + aoff0 + kb);
    gld16(sA + w*1024 + 512, Ap + aoff1 + kb);
    gld16(sB + w*1024,       Bp + boff0 + kb);
    gld16(sB + w*1024 + 512, Bp + boff1 + kb);
    __syncthreads();
    bf16x8 a[4], bb[4];
    #pragma unroll
    for (int m = 0; m < 4; m++)
      a[m] = *(const bf16x8*)&sA[(wr*64 + m*16 + lrow)*32 + fo];
    #pragma unroll
    for (int n = 0; n < 4; n++)
      bb[n] = *(const bf16x8*)&sB[(wc*64 + n*16 + lrow)*32 + fo];
    #pragma unroll
    for (int m = 0; m < 4; m++){
      #pragma unroll
      for (int n = 0; n < 4; n++){
        acc[m][n] = MFMA_BF16(a[m], bb[n], acc[m][n], 0, 0, 0);
      }
    }
    __syncthreads();
  }
  const int r4 = (lane >> 4) * 4;
  #pragma unroll
  for (int m = 0; m < 4; m++){
    #pragma unroll
    for (int n = 0; n < 4; n++){
      #pragma unroll
      for (int j = 0; j < 4; j++){
        const int q = m0 + wr*64 + m*16 + r4 + j;
        const int e = n0 + wc*64 + n*16 + lrow;
        if (q < 1025){
          out[((size_t)b * 1025 + q) * 1024 + e] = acc[m][n][j];
        }
      }
    }
  }
}

// ---------------------------------------------------------------- launch
extern "C" void kernel_launch(void* const* d_in, const int* in_sizes, int n_in,
                              void* d_out, int out_size, void* d_ws, size_t ws_size,
                              hipStream_t stream)
{
  const float* H          = (const float*)d_in[0];
  const float* Wq         = (const float*)d_in[1];
  const float* Wk         = (const float*)d_in[2];
  const float* Wv         = (const float*)d_in[3];
  const float* bias_table = (const float*)d_in[4];
  float* out = (float*)d_out;
  char* ws = (char*)d_ws;

  // workspace layout (bytes), peak 216,465,664:
  //  [0,           33,587,200)  Hhi              -> later Vt  [0, 34,603,008)
  //  [33,587,200,  67,174,400)  Hlo              -> later P   [34,603,008, 69,239,808)
  //  [67,174,400,  69,271,552)  Wqth
  //  [69,271,552,  71,368,704)  Wqtl
  //  [71,368,704,  73,465,856)  Wkth
  //  [73,465,856,  75,563,008)  Wktl
  //  [75,563,008,  77,660,160)  Wvh
  //  [77,660,160,  79,757,312)  GThi
  //  [79,757,312,  81,854,464)  GTlo
  //  [81,854,464, 115,441,664)  HMhi             -> later Vhi [81,854,464, 115,441,664)
  //  [115,441,664,149,028,864)  HMlo
  //  [149,028,864,216,465,664)  scores (f32, stride 1028)
  u16* Hhi  = (u16*)(ws + 0);
  u16* Hlo  = (u16*)(ws + 33587200ull);
  u16* Wqth = (u16*)(ws + 67174400ull);
  u16* Wqtl = (u16*)(ws + 69271552ull);
  u16* Wkth = (u16*)(ws + 71368704ull);
  u16* Wktl = (u16*)(ws + 73465856ull);
  u16* Wvh  = (u16*)(ws + 75563008ull);
  u16* GThi = (u16*)(ws + 77660160ull);
  u16* GTlo = (u16*)(ws + 79757312ull);
  u16* HMhi = (u16*)(ws + 81854464ull);
  u16* HMlo = (u16*)(ws + 115441664ull);
  float* scores = (float*)(ws + 149028864ull);
  u16* Vhi = (u16*)(ws + 81854464ull);   // over HMhi (dead after k_scores)
  u16* Vt  = (u16*)(ws + 0);             // over Hhi (dead after k_projv)
  u16* P   = (u16*)(ws + 34603008ull);   // over Hlo/Wqt (dead after k_scores/k_gt)

  k_split_wt   <<<dim3(32, 32, 3),   256, 0, stream>>>(Wq, Wk, Wv, Wqth, Wqtl, Wkth, Wktl, Wvh);
  k_split_h    <<<dim3(16400, 1, 1), 256, 0, stream>>>(H, Hhi, Hlo);
  k_gt         <<<dim3(8, 8, 1),     256, 0, stream>>>(Wkth, Wktl, Wqth, Wqtl, GThi, GTlo);
  k_ghm        <<<dim3(129, 8, 1),   256, 0, stream>>>(Hhi, Hlo, GThi, GTlo, HMhi, HMlo);
  k_scores     <<<dim3(9, 9, 16),    256, 0, stream>>>(HMhi, HMlo, Hhi, Hlo, bias_table, scores);
  k_projv      <<<dim3(129, 8, 1),   256, 0, stream>>>(Hhi, Wvh, Vhi);
  k_transpose_v<<<dim3(33, 32, 16),  256, 0, stream>>>(Vhi, Vt);
  k_softmax    <<<dim3(16400, 1, 1), 256, 0, stream>>>(scores, P);
  k_pv         <<<dim3(9, 8, 16),    256, 0, stream>>>(P, Vt, out);
}

// Round 6
// 677.577 us; speedup vs baseline: 1.3497x; 1.1227x over previous
//
#include <hip/hip_runtime.h>
#include <math.h>

typedef unsigned short u16;
typedef unsigned int u32;
typedef float f32x4 __attribute__((ext_vector_type(4)));
typedef __bf16 bf16x8 __attribute__((ext_vector_type(8)));
typedef u16 us8 __attribute__((ext_vector_type(8)));
typedef u16 us4 __attribute__((ext_vector_type(4)));

#define MFMA_BF16 __builtin_amdgcn_mfma_f32_16x16x32_bf16

__device__ __forceinline__ u16 f2bf(float x){
  u32 u = __float_as_uint(x);
  u32 r = u + 0x7FFFu + ((u >> 16) & 1u);
  return (u16)(r >> 16);
}
__device__ __forceinline__ float bf2f(u16 h){ return __uint_as_float(((u32)h) << 16); }

// async global->LDS, 16B per lane; lds base must be wave-uniform (HW scatters lane*16)
__device__ __forceinline__ void gld16(u16* lds, const char* g){
  __builtin_amdgcn_global_load_lds((const __attribute__((address_space(1))) void*)g,
                                   (__attribute__((address_space(3))) void*)lds,
                                   16, 0, 0);
}

// ---------------------------------------------------------------- split(+transpose) weights
__global__ __launch_bounds__(256) void k_split_wt(const float* __restrict__ Wq,
                                                  const float* __restrict__ Wk,
                                                  const float* __restrict__ Wv,
                                                  u16* __restrict__ Wqth, u16* __restrict__ Wqtl,
                                                  u16* __restrict__ Wkth, u16* __restrict__ Wktl,
                                                  u16* __restrict__ Wvh){
  const int z = blockIdx.z;
  const int r0 = blockIdx.y * 32, c0 = blockIdx.x * 32;
  const int tx = threadIdx.x & 31, ty = threadIdx.x >> 5;
  if (z == 2){
    #pragma unroll
    for (int i = 0; i < 4; i++){
      const int r = r0 + ty + i * 8;
      Wvh[(size_t)r * 1024 + c0 + tx] = f2bf(Wv[(size_t)r * 1024 + c0 + tx]);
    }
    return;
  }
  const float* __restrict__ W = (z == 0) ? Wq : Wk;
  u16* __restrict__ hi = (z == 0) ? Wqth : Wkth;
  u16* __restrict__ lo = (z == 0) ? Wqtl : Wktl;
  __shared__ float T[32][33];
  #pragma unroll
  for (int i = 0; i < 4; i++){
    T[ty + i*8][tx] = W[(size_t)(r0 + ty + i*8) * 1024 + c0 + tx];
  }
  __syncthreads();
  #pragma unroll
  for (int i = 0; i < 4; i++){
    const float v = T[tx][ty + i*8];
    const u16 h = f2bf(v);
    const size_t o = (size_t)(c0 + ty + i*8) * 1024 + r0 + tx;
    hi[o] = h;
    lo[o] = f2bf(v - bf2f(h));
  }
}

// ---------------------------------------------------------------- split H
__global__ __launch_bounds__(256) void k_split_h(const float* __restrict__ H,
                                                 u16* __restrict__ Hhi, u16* __restrict__ Hlo){
  const size_t row = blockIdx.x;
  const int i = threadIdx.x * 4;
  f32x4 v = *(const f32x4*)(H + row * 1024 + i);
  u16 h[4], l[4];
  #pragma unroll
  for (int j = 0; j < 4; j++){
    h[j] = f2bf(v[j]);
    l[j] = f2bf(v[j] - bf2f(h[j]));
  }
  *(us4*)&Hhi[row * 1024 + i] = *(const us4*)&h[0];
  *(us4*)&Hlo[row * 1024 + i] = *(const us4*)&l[0];
}

// ---------------------------------------------------------------- GT = Wk^T Wq (3-pass, split output)
__global__ __launch_bounds__(256) void k_gt(
    const u16* __restrict__ Akth, const u16* __restrict__ Aktl,
    const u16* __restrict__ Bqth, const u16* __restrict__ Bqtl,
    u16* __restrict__ GThi, u16* __restrict__ GTlo)
{
  __shared__ __align__(16) u16 sAh[128*32];
  __shared__ __align__(16) u16 sAl[128*32];
  __shared__ __align__(16) u16 sBh[128*32];
  __shared__ __align__(16) u16 sBl[128*32];
  const int tid = threadIdx.x, lane = tid & 63, w = tid >> 6;
  const int m0 = blockIdx.x * 128, n0 = blockIdx.y * 128;

  const int sr = w * 32 + (lane >> 2);
  const int cb = (lane & 3) * 16;
  const size_t aoff0 = (size_t)(m0 + sr)      * 2048 + cb;
  const size_t aoff1 = (size_t)(m0 + sr + 16) * 2048 + cb;
  const size_t boff0 = (size_t)(n0 + sr)      * 2048 + cb;
  const size_t boff1 = (size_t)(n0 + sr + 16) * 2048 + cb;
  const char* Ah = (const char*)Akth;
  const char* Al = (const char*)Aktl;
  const char* Bh = (const char*)Bqth;
  const char* Bl = (const char*)Bqtl;

  const int wr = w >> 1, wc = w & 1;
  const int lrow = lane & 15;
  const int fo = (lane >> 4) * 8;

  f32x4 acc[4][4] = {};

  for (int k0 = 0; k0 < 1024; k0 += 32){
    const size_t kb = (size_t)k0 * 2;
    gld16(sAh + w*1024,       Ah + aoff0 + kb);
    gld16(sAh + w*1024 + 512, Ah + aoff1 + kb);
    gld16(sAl + w*1024,       Al + aoff0 + kb);
    gld16(sAl + w*1024 + 512, Al + aoff1 + kb);
    gld16(sBh + w*1024,       Bh + boff0 + kb);
    gld16(sBh + w*1024 + 512, Bh + boff1 + kb);
    gld16(sBl + w*1024,       Bl + boff0 + kb);
    gld16(sBl + w*1024 + 512, Bl + boff1 + kb);
    __syncthreads();
    bf16x8 ah[4], al[4], bh[4], bl[4];
    #pragma unroll
    for (int m = 0; m < 4; m++){
      ah[m] = *(const bf16x8*)&sAh[(wr*64 + m*16 + lrow)*32 + fo];
      al[m] = *(const bf16x8*)&sAl[(wr*64 + m*16 + lrow)*32 + fo];
    }
    #pragma unroll
    for (int n = 0; n < 4; n++){
      bh[n] = *(const bf16x8*)&sBh[(wc*64 + n*16 + lrow)*32 + fo];
      bl[n] = *(const bf16x8*)&sBl[(wc*64 + n*16 + lrow)*32 + fo];
    }
    #pragma unroll
    for (int m = 0; m < 4; m++){
      #pragma unroll
      for (int n = 0; n < 4; n++){
        acc[m][n] = MFMA_BF16(ah[m], bh[n], acc[m][n], 0, 0, 0);
        acc[m][n] = MFMA_BF16(ah[m], bl[n], acc[m][n], 0, 0, 0);
        acc[m][n] = MFMA_BF16(al[m], bh[n], acc[m][n], 0, 0, 0);
      }
    }
    __syncthreads();
  }
  const int r4 = (lane >> 4) * 4;
  #pragma unroll
  for (int m = 0; m < 4; m++){
    #pragma unroll
    for (int n = 0; n < 4; n++){
      #pragma unroll
      for (int j = 0; j < 4; j++){
        const int row = m0 + wr*64 + m*16 + r4 + j;
        const int col = n0 + wc*64 + n*16 + lrow;
        const float v = acc[m][n][j];
        const size_t o = (size_t)row * 1024 + col;
        const u16 h = f2bf(v);
        GThi[o] = h;
        GTlo[o] = f2bf(v - bf2f(h));
      }
    }
  }
}

// ---------------------------------------------------------------- HM = H . GT (3-pass, split output)
// 2-phase dbuf prefetch; grid linear 1032, XCD-chunked, n-fastest (A-panel reuse per XCD)
__global__ __launch_bounds__(256) void k_ghm(
    const u16* __restrict__ Hhi, const u16* __restrict__ Hlo,
    const u16* __restrict__ GThi, const u16* __restrict__ GTlo,
    u16* __restrict__ HMhi, u16* __restrict__ HMlo)
{
  __shared__ __align__(16) u16 sAh[2][4096];
  __shared__ __align__(16) u16 sAl[2][4096];
  __shared__ __align__(16) u16 sBh[2][4096];
  __shared__ __align__(16) u16 sBl[2][4096];
  const int tid = threadIdx.x, lane = tid & 63, w = tid >> 6;
  const int hw = blockIdx.x;
  const int wg = (hw & 7) * 129 + (hw >> 3);
  const int m0 = (wg >> 3) * 128;
  const int n0 = (wg & 7) * 128;

  const int sr = w * 32 + (lane >> 2);
  const int cb = (lane & 3) * 16;
  const size_t aoff0 = (size_t)min(m0 + sr,      16399) * 2048 + cb;
  const size_t aoff1 = (size_t)min(m0 + sr + 16, 16399) * 2048 + cb;
  const size_t boff0 = (size_t)(n0 + sr)      * 2048 + cb;
  const size_t boff1 = (size_t)(n0 + sr + 16) * 2048 + cb;
  const char* Ah = (const char*)Hhi;
  const char* Al = (const char*)Hlo;
  const char* Bh = (const char*)GThi;
  const char* Bl = (const char*)GTlo;

  const int wr = w >> 1, wc = w & 1;
  const int lrow = lane & 15;
  const int fo = (lane >> 4) * 8;

#define STAGE_GHM(buf, kb) \
    gld16(&sAh[buf][w*1024],       Ah + aoff0 + (kb)); \
    gld16(&sAh[buf][w*1024 + 512], Ah + aoff1 + (kb)); \
    gld16(&sAl[buf][w*1024],       Al + aoff0 + (kb)); \
    gld16(&sAl[buf][w*1024 + 512], Al + aoff1 + (kb)); \
    gld16(&sBh[buf][w*1024],       Bh + boff0 + (kb)); \
    gld16(&sBh[buf][w*1024 + 512], Bh + boff1 + (kb)); \
    gld16(&sBl[buf][w*1024],       Bl + boff0 + (kb)); \
    gld16(&sBl[buf][w*1024 + 512], Bl + boff1 + (kb));

  f32x4 acc[4][4] = {};
  STAGE_GHM(0, 0)
  __syncthreads();
  int cur = 0;
  for (int t = 0; t < 32; ++t){
    if (t < 31){ STAGE_GHM(cur ^ 1, (size_t)(t + 1) * 64) }
    bf16x8 ah[4], al[4], bh[4], bl[4];
    #pragma unroll
    for (int m = 0; m < 4; m++){
      ah[m] = *(const bf16x8*)&sAh[cur][(wr*64 + m*16 + lrow)*32 + fo];
      al[m] = *(const bf16x8*)&sAl[cur][(wr*64 + m*16 + lrow)*32 + fo];
    }
    #pragma unroll
    for (int n = 0; n < 4; n++){
      bh[n] = *(const bf16x8*)&sBh[cur][(wc*64 + n*16 + lrow)*32 + fo];
      bl[n] = *(const bf16x8*)&sBl[cur][(wc*64 + n*16 + lrow)*32 + fo];
    }
    #pragma unroll
    for (int m = 0; m < 4; m++){
      #pragma unroll
      for (int n = 0; n < 4; n++){
        acc[m][n] = MFMA_BF16(ah[m], bh[n], acc[m][n], 0, 0, 0);
        acc[m][n] = MFMA_BF16(ah[m], bl[n], acc[m][n], 0, 0, 0);
        acc[m][n] = MFMA_BF16(al[m], bh[n], acc[m][n], 0, 0, 0);
      }
    }
    __syncthreads();
    cur ^= 1;
  }
#undef STAGE_GHM
  const int r4 = (lane >> 4) * 4;
  #pragma unroll
  for (int m = 0; m < 4; m++){
    #pragma unroll
    for (int n = 0; n < 4; n++){
      #pragma unroll
      for (int j = 0; j < 4; j++){
        const int row = m0 + wr*64 + m*16 + r4 + j;
        const int col = n0 + wc*64 + n*16 + lrow;
        if (row < 16400){
          const float v = acc[m][n][j];
          const size_t o = (size_t)row * 1024 + col;
          const u16 h = f2bf(v);
          HMhi[o] = h;
          HMlo[o] = f2bf(v - bf2f(h));
        }
      }
    }
  }
}

// ---------------------------------------------------------------- scores = HM . H^T (+bias)
// 2-phase dbuf prefetch; grid linear 1296, XCD-chunked (one batch per half-chunk), m-fastest
__global__ __launch_bounds__(256) void k_scores(
    const u16* __restrict__ HMhi, const u16* __restrict__ HMlo,
    const u16* __restrict__ Hhi, const u16* __restrict__ Hlo,
    const float* __restrict__ bias_table, float* __restrict__ scores)
{
  __shared__ __align__(16) u16 sAh[2][4096];
  __shared__ __align__(16) u16 sAl[2][4096];
  __shared__ __align__(16) u16 sBh[2][4096];
  __shared__ __align__(16) u16 sBl[2][4096];
  const int tid = threadIdx.x, lane = tid & 63, w = tid >> 6;
  const int hw = blockIdx.x;
  const int wg = (hw & 7) * 162 + (hw >> 3);
  const int b = wg / 81;
  const int rem = wg % 81;
  const int m0 = (rem % 9) * 128, n0 = (rem / 9) * 128;

  const int sr = w * 32 + (lane >> 2);
  const int cb = (lane & 3) * 16;
  const size_t aoff0 = ((size_t)b*1025 + min(m0 + sr,      1024)) * 2048 + cb;
  const size_t aoff1 = ((size_t)b*1025 + min(m0 + sr + 16, 1024)) * 2048 + cb;
  const size_t boff0 = ((size_t)b*1025 + min(n0 + sr,      1024)) * 2048 + cb;
  const size_t boff1 = ((size_t)b*1025 + min(n0 + sr + 16, 1024)) * 2048 + cb;
  const char* Ah = (const char*)HMhi;
  const char* Al = (const char*)HMlo;
  const char* Bh = (const char*)Hhi;
  const char* Bl = (const char*)Hlo;

  const int wr = w >> 1, wc = w & 1;
  const int lrow = lane & 15;
  const int fo = (lane >> 4) * 8;

#define STAGE_SC(buf, kb) \
    gld16(&sAh[buf][w*1024],       Ah + aoff0 + (kb)); \
    gld16(&sAh[buf][w*1024 + 512], Ah + aoff1 + (kb)); \
    gld16(&sAl[buf][w*1024],       Al + aoff0 + (kb)); \
    gld16(&sAl[buf][w*1024 + 512], Al + aoff1 + (kb)); \
    gld16(&sBh[buf][w*1024],       Bh + boff0 + (kb)); \
    gld16(&sBh[buf][w*1024 + 512], Bh + boff1 + (kb)); \
    gld16(&sBl[buf][w*1024],       Bl + boff0 + (kb)); \
    gld16(&sBl[buf][w*1024 + 512], Bl + boff1 + (kb));

  f32x4 acc[4][4] = {};
  STAGE_SC(0, 0)
  __syncthreads();
  int cur = 0;
  for (int t = 0; t < 32; ++t){
    if (t < 31){ STAGE_SC(cur ^ 1, (size_t)(t + 1) * 64) }
    bf16x8 ah[4], al[4], bh[4], bl[4];
    #pragma unroll
    for (int m = 0; m < 4; m++){
      ah[m] = *(const bf16x8*)&sAh[cur][(wr*64 + m*16 + lrow)*32 + fo];
      al[m] = *(const bf16x8*)&sAl[cur][(wr*64 + m*16 + lrow)*32 + fo];
    }
    #pragma unroll
    for (int n = 0; n < 4; n++){
      bh[n] = *(const bf16x8*)&sBh[cur][(wc*64 + n*16 + lrow)*32 + fo];
      bl[n] = *(const bf16x8*)&sBl[cur][(wc*64 + n*16 + lrow)*32 + fo];
    }
    #pragma unroll
    for (int m = 0; m < 4; m++){
      #pragma unroll
      for (int n = 0; n < 4; n++){
        acc[m][n] = MFMA_BF16(ah[m], bh[n], acc[m][n], 0, 0, 0);
        acc[m][n] = MFMA_BF16(ah[m], bl[n], acc[m][n], 0, 0, 0);
        acc[m][n] = MFMA_BF16(al[m], bh[n], acc[m][n], 0, 0, 0);
      }
    }
    __syncthreads();
    cur ^= 1;
  }
#undef STAGE_SC
  const int r4 = (lane >> 4) * 4;
  #pragma unroll
  for (int m = 0; m < 4; m++){
    #pragma unroll
    for (int n = 0; n < 4; n++){
      #pragma unroll
      for (int j = 0; j < 4; j++){
        const int q  = m0 + wr*64 + m*16 + r4 + j;
        const int kk = n0 + wc*64 + n*16 + lrow;
        if (q < 1025 && kk < 1025){
          float v = acc[m][n][j];
          if (q > 0 && kk > 0){
            const int i = q - 1, jj = kk - 1;
            const int yi = i >> 5, xi = i & 31;
            const int yj = jj >> 5, xj = jj & 31;
            const int idx = (yi - yj + 31) * 63 + (xi - xj + 31);
            v += bias_table[idx * 16 + b];
          }
          scores[((size_t)b * 1025 + q) * 1028 + kk] = v;
        }
      }
    }
  }
}

// ---------------------------------------------------------------- V projection GEMM (1-pass, dbuf)
__global__ __launch_bounds__(256) void k_projv(
    const u16* __restrict__ Hhi, const u16* __restrict__ Wvh,
    u16* __restrict__ Vhi)
{
  __shared__ __align__(16) u16 sA[2][4096];
  __shared__ __align__(16) u16 sB[2][4096];
  const int tid = threadIdx.x, lane = tid & 63, w = tid >> 6;
  const int hw = blockIdx.x;
  const int wg = (hw & 7) * 129 + (hw >> 3);
  const int m0 = (wg >> 3) * 128;
  const int n0 = (wg & 7) * 128;

  const int sr  = w * 32 + (lane >> 2);
  const int cb  = (lane & 3) * 16;
  const size_t aoff0 = (size_t)min(m0 + sr,      16399) * 2048 + cb;
  const size_t aoff1 = (size_t)min(m0 + sr + 16, 16399) * 2048 + cb;
  const size_t boff0 = (size_t)(n0 + sr)      * 2048 + cb;
  const size_t boff1 = (size_t)(n0 + sr + 16) * 2048 + cb;
  const char* Ah = (const char*)Hhi;
  const char* Bh = (const char*)Wvh;

  const int wr = w >> 1, wc = w & 1;
  const int lrow = lane & 15;
  const int fo = (lane >> 4) * 8;

#define STAGE_PV(buf, kb) \
    gld16(&sA[buf][w*1024],       Ah + aoff0 + (kb)); \
    gld16(&sA[buf][w*1024 + 512], Ah + aoff1 + (kb)); \
    gld16(&sB[buf][w*1024],       Bh + boff0 + (kb)); \
    gld16(&sB[buf][w*1024 + 512], Bh + boff1 + (kb));

  f32x4 acc[4][4] = {};
  STAGE_PV(0, 0)
  __syncthreads();
  int cur = 0;
  for (int t = 0; t < 32; ++t){
    if (t < 31){ STAGE_PV(cur ^ 1, (size_t)(t + 1) * 64) }
    bf16x8 a[4], bb[4];
    #pragma unroll
    for (int m = 0; m < 4; m++) a[m]  = *(const bf16x8*)&sA[cur][(wr*64 + m*16 + lrow)*32 + fo];
    #pragma unroll
    for (int n = 0; n < 4; n++) bb[n] = *(const bf16x8*)&sB[cur][(wc*64 + n*16 + lrow)*32 + fo];
    #pragma unroll
    for (int m = 0; m < 4; m++){
      #pragma unroll
      for (int n = 0; n < 4; n++){
        acc[m][n] = MFMA_BF16(a[m], bb[n], acc[m][n], 0, 0, 0);
      }
    }
    __syncthreads();
    cur ^= 1;
  }
#undef STAGE_PV
  const int r4 = (lane >> 4) * 4;
  #pragma unroll
  for (int m = 0; m < 4; m++){
    #pragma unroll
    for (int n = 0; n < 4; n++){
      #pragma unroll
      for (int j = 0; j < 4; j++){
        const int row = m0 + wr*64 + m*16 + r4 + j;
        const int col = n0 + wc*64 + n*16 + lrow;
        if (row < 16400){
          Vhi[(size_t)row * 1024 + col] = f2bf(acc[m][n][j]);
        }
      }
    }
  }
}

// ---------------------------------------------------------------- V transpose  (Vt stride 1056, pad cols zeroed)
__global__ __launch_bounds__(256) void k_transpose_v(const u16* __restrict__ Vhi,
                                                     u16* __restrict__ Vt){
  __shared__ u16 T[32][33];
  const int b = blockIdx.z, s0 = blockIdx.x * 32, e0 = blockIdx.y * 32;
  const int tx = threadIdx.x & 31, ty = threadIdx.x >> 5;
  #pragma unroll
  for (int i = 0; i < 4; i++){
    const int s = s0 + ty + i * 8;
    T[ty + i*8][tx] = (s < 1025) ? Vhi[((size_t)b * 1025 + s) * 1024 + e0 + tx] : (u16)0;
  }
  __syncthreads();
  #pragma unroll
  for (int i = 0; i < 4; i++){
    const int e = e0 + ty + i * 8;
    const int s = s0 + tx;
    Vt[((size_t)b * 1024 + e) * 1056 + s] = T[tx][ty + i*8];
  }
}

// ---------------------------------------------------------------- softmax  (P stride 1056, pad cols zeroed)
__global__ __launch_bounds__(256) void k_softmax(const float* __restrict__ scores,
                                                 u16* __restrict__ P){
  __shared__ float red[4];
  const int tid = threadIdx.x;
  const size_t R = blockIdx.x;
  const float* __restrict__ row = scores + R * 1028;
  f32x4 v = *(const f32x4*)&row[tid * 4];
  const float extra = (tid == 0) ? row[1024] : -1e30f;
  float mx = fmaxf(fmaxf(v[0], v[1]), fmaxf(v[2], v[3]));
  mx = fmaxf(mx, extra);
  #pragma unroll
  for (int off = 32; off >= 1; off >>= 1) mx = fmaxf(mx, __shfl_down(mx, off, 64));
  if ((tid & 63) == 0) red[tid >> 6] = mx;
  __syncthreads();
  mx = fmaxf(fmaxf(red[0], red[1]), fmaxf(red[2], red[3]));
  __syncthreads();
  f32x4 e;
  e[0] = __expf(v[0] - mx); e[1] = __expf(v[1] - mx);
  e[2] = __expf(v[2] - mx); e[3] = __expf(v[3] - mx);
  const float e4 = (tid == 0) ? __expf(extra - mx) : 0.f;
  float s = e[0] + e[1] + e[2] + e[3] + e4;
  #pragma unroll
  for (int off = 32; off >= 1; off >>= 1) s += __shfl_down(s, off, 64);
  if ((tid & 63) == 0) red[tid >> 6] = s;
  __syncthreads();
  s = red[0] + red[1] + red[2] + red[3];
  const float inv = 1.0f / s;
  u16 p[4];
  p[0] = f2bf(e[0] * inv); p[1] = f2bf(e[1] * inv);
  p[2] = f2bf(e[2] * inv); p[3] = f2bf(e[3] * inv);
  *(us4*)&P[R * 1056 + tid * 4] = *(const us4*)&p[0];
  if (tid < 32){
    P[R * 1056 + 1024 + tid] = (tid == 0) ? f2bf(e4 * inv) : (u16)0;
  }
}

// ---------------------------------------------------------------- PV GEMM (dbuf, swizzled)
__global__ __launch_bounds__(256) void k_pv(const u16* __restrict__ P,
                                            const u16* __restrict__ Vt,
                                            float* __restrict__ out)
{
  __shared__ __align__(16) u16 sA[2][4096];
  __shared__ __align__(16) u16 sB[2][4096];
  const int tid = threadIdx.x, lane = tid & 63, w = tid >> 6;
  const int hw = blockIdx.x;
  const int wg = (hw & 7) * 144 + (hw >> 3);
  const int b = wg / 72;
  const int rem = wg % 72;
  const int m0 = (rem >> 3) * 128;
  const int n0 = (rem & 7) * 128;

  const int sr = w * 32 + (lane >> 2);
  const int cb = (lane & 3) * 16;
  const size_t aoff0 = ((size_t)b*1025 + min(m0 + sr,      1024)) * 2112 + cb;
  const size_t aoff1 = ((size_t)b*1025 + min(m0 + sr + 16, 1024)) * 2112 + cb;
  const size_t boff0 = ((size_t)b*1024 + n0 + sr)      * 2112 + cb;
  const size_t boff1 = ((size_t)b*1024 + n0 + sr + 16) * 2112 + cb;
  const char* Ap = (const char*)P;
  const char* Bp = (const char*)Vt;

  const int wr = w >> 1, wc = w & 1;
  const int lrow = lane & 15;
  const int fo = (lane >> 4) * 8;

#define STAGE_KPV(buf, kb) \
    gld16(&sA[buf][w*1024],       Ap + aoff0 + (kb)); \
    gld16(&sA[buf][w*1024 + 512], Ap + aoff1 + (kb)); \
    gld16(&sB[buf][w*1024],       Bp + boff0 + (kb)); \
    gld16(&sB[buf][w*1024 + 512], Bp + boff1 + (kb));

  f32x4 acc[4][4] = {};
  STAGE_KPV(0, 0)
  __syncthreads();
  int cur = 0;
  for (int t = 0; t < 33; ++t){
    if (t < 32){ STAGE_KPV(cur ^ 1, (size_t)(t + 1) * 64) }
    bf16x8 a[4], bb[4];
    #pragma unroll
    for (int m = 0; m < 4; m++)
      a[m] = *(const bf16x8*)&sA[cur][(wr*64 + m*16 + lrow)*32 + fo];
    #pragma unroll
    for (int n = 0; n < 4; n++)
      bb[n] = *(const bf16x8*)&sB[cur][(wc*64 + n*16 + lrow)*32 + fo];
    #pragma unroll
    for (int m = 0; m < 4; m++){
      #pragma unroll
      for (int n = 0; n < 4; n++){
        acc[m][n] = MFMA_BF16(a[m], bb[n], acc[m][n], 0, 0, 0);
      }
    }
    __syncthreads();
    cur ^= 1;
  }
#undef STAGE_KPV
  const int r4 = (lane >> 4) * 4;
  #pragma unroll
  for (int m = 0; m < 4; m++){
    #pragma unroll
    for (int n = 0; n < 4; n++){
      #pragma unroll
      for (int j = 0; j < 4; j++){
        const int q = m0 + wr*64 + m*16 + r4 + j;
        const int e = n0 + wc*64 + n*16 + lrow;
        if (q < 1025){
          out[((size_t)b * 1025 + q) * 1024 + e] = acc[m][n][j];
        }
      }
    }
  }
}

// ---------------------------------------------------------------- launch
extern "C" void kernel_launch(void* const* d_in, const int* in_sizes, int n_in,
                              void* d_out, int out_size, void* d_ws, size_t ws_size,
                              hipStream_t stream)
{
  const float* H          = (const float*)d_in[0];
  const float* Wq         = (const float*)d_in[1];
  const float* Wk         = (const float*)d_in[2];
  const float* Wv         = (const float*)d_in[3];
  const float* bias_table = (const float*)d_in[4];
  float* out = (float*)d_out;
  char* ws = (char*)d_ws;

  u16* Hhi  = (u16*)(ws + 0);
  u16* Hlo  = (u16*)(ws + 33587200ull);
  u16* Wqth = (u16*)(ws + 67174400ull);
  u16* Wqtl = (u16*)(ws + 69271552ull);
  u16* Wkth = (u16*)(ws + 71368704ull);
  u16* Wktl = (u16*)(ws + 73465856ull);
  u16* Wvh  = (u16*)(ws + 75563008ull);
  u16* GThi = (u16*)(ws + 77660160ull);
  u16* GTlo = (u16*)(ws + 79757312ull);
  u16* HMhi = (u16*)(ws + 81854464ull);
  u16* HMlo = (u16*)(ws + 115441664ull);
  float* scores = (float*)(ws + 149028864ull);
  u16* Vhi = (u16*)(ws + 81854464ull);   // over HMhi (dead after k_scores)
  u16* Vt  = (u16*)(ws + 0);             // over Hhi (dead after k_projv)
  u16* P   = (u16*)(ws + 34603008ull);   // over Hlo/Wqt (dead after k_scores/k_gt)

  k_split_wt   <<<dim3(32, 32, 3),   256, 0, stream>>>(Wq, Wk, Wv, Wqth, Wqtl, Wkth, Wktl, Wvh);
  k_split_h    <<<dim3(16400, 1, 1), 256, 0, stream>>>(H, Hhi, Hlo);
  k_gt         <<<dim3(8, 8, 1),     256, 0, stream>>>(Wkth, Wktl, Wqth, Wqtl, GThi, GTlo);
  k_ghm        <<<dim3(1032, 1, 1),  256, 0, stream>>>(Hhi, Hlo, GThi, GTlo, HMhi, HMlo);
  k_scores     <<<dim3(1296, 1, 1),  256, 0, stream>>>(HMhi, HMlo, Hhi, Hlo, bias_table, scores);
  k_projv      <<<dim3(1032, 1, 1),  256, 0, stream>>>(Hhi, Wvh, Vhi);
  k_transpose_v<<<dim3(33, 32, 16),  256, 0, stream>>>(Vhi, Vt);
  k_softmax    <<<dim3(16400, 1, 1), 256, 0, stream>>>(scores, P);
  k_pv         <<<dim3(1152, 1, 1),  256, 0, stream>>>(P, Vt, out);
}

// Round 7
// 499.789 us; speedup vs baseline: 1.8298x; 1.3557x over previous
//
#include <hip/hip_runtime.h>
#include <math.h>

typedef unsigned short u16;
typedef unsigned int u32;
typedef _Float16 f16;
typedef float f32x4 __attribute__((ext_vector_type(4)));
typedef f16 f16x8 __attribute__((ext_vector_type(8)));
typedef f16 f16x4 __attribute__((ext_vector_type(4)));

#define MFMA_F16 __builtin_amdgcn_mfma_f32_16x16x32_f16

// async global->LDS, 16B per lane; lds base must be wave-uniform (HW scatters lane*16)
__device__ __forceinline__ void gld16(void* lds, const char* g){
  __builtin_amdgcn_global_load_lds((const __attribute__((address_space(1))) void*)g,
                                   (__attribute__((address_space(3))) void*)lds,
                                   16, 0, 0);
}

// ---------------------------------------------------------------- convert(+transpose) weights -> fp16
// z=0: Wq -> Wqt (transposed). z=1: Wk -> Wkt (transposed). z=2: Wv -> Wvh (plain).
__global__ __launch_bounds__(256) void k_split_wt(const float* __restrict__ Wq,
                                                  const float* __restrict__ Wk,
                                                  const float* __restrict__ Wv,
                                                  f16* __restrict__ Wqt, f16* __restrict__ Wkt,
                                                  f16* __restrict__ Wvh){
  const int z = blockIdx.z;
  const int r0 = blockIdx.y * 32, c0 = blockIdx.x * 32;
  const int tx = threadIdx.x & 31, ty = threadIdx.x >> 5;
  if (z == 2){
    #pragma unroll
    for (int i = 0; i < 4; i++){
      const int r = r0 + ty + i * 8;
      Wvh[(size_t)r * 1024 + c0 + tx] = (f16)Wv[(size_t)r * 1024 + c0 + tx];
    }
    return;
  }
  const float* __restrict__ W = (z == 0) ? Wq : Wk;
  f16* __restrict__ o = (z == 0) ? Wqt : Wkt;
  __shared__ float T[32][33];
  #pragma unroll
  for (int i = 0; i < 4; i++){
    T[ty + i*8][tx] = W[(size_t)(r0 + ty + i*8) * 1024 + c0 + tx];
  }
  __syncthreads();
  #pragma unroll
  for (int i = 0; i < 4; i++){
    o[(size_t)(c0 + ty + i*8) * 1024 + r0 + tx] = (f16)T[tx][ty + i*8];
  }
}

// ---------------------------------------------------------------- convert H -> fp16
__global__ __launch_bounds__(256) void k_prep_h(const float* __restrict__ H,
                                                f16* __restrict__ Hh){
  const size_t row = blockIdx.x;
  const int i = threadIdx.x * 4;
  f32x4 v = *(const f32x4*)(H + row * 1024 + i);
  f16x4 h;
  h[0] = (f16)v[0]; h[1] = (f16)v[1]; h[2] = (f16)v[2]; h[3] = (f16)v[3];
  *(f16x4*)&Hh[row * 1024 + i] = h;
}

// ================================================================ GEMM template pieces
// All tiled GEMMs: 128x128 tile, BK=32, 4 waves, dbuf LDS, swizzled 16B slots.
// write-side slot perm: lane fetches logical slot (lane&3)^((lane>>3)&3)
// read-side:            fo = ((lane>>4)^((lane>>1)&3))*8 elems

// ---------------------------------------------------------------- GT = Wk^T Wq  (GT[d',d], fp16 out)
__global__ __launch_bounds__(256) void k_gt(
    const f16* __restrict__ Wkt, const f16* __restrict__ Wqt,
    f16* __restrict__ GT)
{
  __shared__ __align__(16) f16 sA[2][4096];
  __shared__ __align__(16) f16 sB[2][4096];
  const int tid = threadIdx.x, lane = tid & 63, w = tid >> 6;
  const int m0 = blockIdx.x * 128, n0 = blockIdx.y * 128;

  const int sr = w * 32 + (lane >> 2);
  const int cb = (((lane & 3) ^ ((lane >> 3) & 3))) * 16;
  const size_t aoff0 = (size_t)(m0 + sr)      * 2048 + cb;
  const size_t aoff1 = (size_t)(m0 + sr + 16) * 2048 + cb;
  const size_t boff0 = (size_t)(n0 + sr)      * 2048 + cb;
  const size_t boff1 = (size_t)(n0 + sr + 16) * 2048 + cb;
  const char* Ap = (const char*)Wkt;
  const char* Bp = (const char*)Wqt;

  const int wr = w >> 1, wc = w & 1;
  const int lrow = lane & 15;
  const int fo = (((lane >> 4) ^ ((lane >> 1) & 3))) * 8;

#define STAGE(buf, kb) \
    gld16(&sA[buf][w*1024],       Ap + aoff0 + (kb)); \
    gld16(&sA[buf][w*1024 + 512], Ap + aoff1 + (kb)); \
    gld16(&sB[buf][w*1024],       Bp + boff0 + (kb)); \
    gld16(&sB[buf][w*1024 + 512], Bp + boff1 + (kb));

  f32x4 acc[4][4] = {};
  STAGE(0, 0)
  __syncthreads();
  int cur = 0;
  for (int t = 0; t < 32; ++t){
    if (t < 31){ STAGE(cur ^ 1, (size_t)(t + 1) * 64) }
    f16x8 a[4], bb[4];
    #pragma unroll
    for (int m = 0; m < 4; m++) a[m]  = *(const f16x8*)&sA[cur][(wr*64 + m*16 + lrow)*32 + fo];
    #pragma unroll
    for (int n = 0; n < 4; n++) bb[n] = *(const f16x8*)&sB[cur][(wc*64 + n*16 + lrow)*32 + fo];
    #pragma unroll
    for (int m = 0; m < 4; m++)
      #pragma unroll
      for (int n = 0; n < 4; n++)
        acc[m][n] = MFMA_F16(a[m], bb[n], acc[m][n], 0, 0, 0);
    __syncthreads();
    cur ^= 1;
  }
#undef STAGE
  const int r4 = (lane >> 4) * 4;
  #pragma unroll
  for (int m = 0; m < 4; m++)
    #pragma unroll
    for (int n = 0; n < 4; n++)
      #pragma unroll
      for (int j = 0; j < 4; j++){
        const int row = m0 + wr*64 + m*16 + r4 + j;
        const int col = n0 + wc*64 + n*16 + lrow;
        GT[(size_t)row * 1024 + col] = (f16)acc[m][n][j];
      }
}

// ---------------------------------------------------------------- HM = H . GT^row  (fp16 out)
__global__ __launch_bounds__(256) void k_ghm(
    const f16* __restrict__ Hh, const f16* __restrict__ GT,
    f16* __restrict__ HM)
{
  __shared__ __align__(16) f16 sA[2][4096];
  __shared__ __align__(16) f16 sB[2][4096];
  const int tid = threadIdx.x, lane = tid & 63, w = tid >> 6;
  const int hw = blockIdx.x;
  const int wg = (hw & 7) * 129 + (hw >> 3);
  const int m0 = (wg >> 3) * 128;
  const int n0 = (wg & 7) * 128;

  const int sr = w * 32 + (lane >> 2);
  const int cb = (((lane & 3) ^ ((lane >> 3) & 3))) * 16;
  const size_t aoff0 = (size_t)min(m0 + sr,      16399) * 2048 + cb;
  const size_t aoff1 = (size_t)min(m0 + sr + 16, 16399) * 2048 + cb;
  const size_t boff0 = (size_t)(n0 + sr)      * 2048 + cb;
  const size_t boff1 = (size_t)(n0 + sr + 16) * 2048 + cb;
  const char* Ap = (const char*)Hh;
  const char* Bp = (const char*)GT;

  const int wr = w >> 1, wc = w & 1;
  const int lrow = lane & 15;
  const int fo = (((lane >> 4) ^ ((lane >> 1) & 3))) * 8;

#define STAGE(buf, kb) \
    gld16(&sA[buf][w*1024],       Ap + aoff0 + (kb)); \
    gld16(&sA[buf][w*1024 + 512], Ap + aoff1 + (kb)); \
    gld16(&sB[buf][w*1024],       Bp + boff0 + (kb)); \
    gld16(&sB[buf][w*1024 + 512], Bp + boff1 + (kb));

  f32x4 acc[4][4] = {};
  STAGE(0, 0)
  __syncthreads();
  int cur = 0;
  for (int t = 0; t < 32; ++t){
    if (t < 31){ STAGE(cur ^ 1, (size_t)(t + 1) * 64) }
    f16x8 a[4], bb[4];
    #pragma unroll
    for (int m = 0; m < 4; m++) a[m]  = *(const f16x8*)&sA[cur][(wr*64 + m*16 + lrow)*32 + fo];
    #pragma unroll
    for (int n = 0; n < 4; n++) bb[n] = *(const f16x8*)&sB[cur][(wc*64 + n*16 + lrow)*32 + fo];
    #pragma unroll
    for (int m = 0; m < 4; m++)
      #pragma unroll
      for (int n = 0; n < 4; n++)
        acc[m][n] = MFMA_F16(a[m], bb[n], acc[m][n], 0, 0, 0);
    __syncthreads();
    cur ^= 1;
  }
#undef STAGE
  const int r4 = (lane >> 4) * 4;
  #pragma unroll
  for (int m = 0; m < 4; m++)
    #pragma unroll
    for (int n = 0; n < 4; n++)
      #pragma unroll
      for (int j = 0; j < 4; j++){
        const int row = m0 + wr*64 + m*16 + r4 + j;
        const int col = n0 + wc*64 + n*16 + lrow;
        if (row < 16400) HM[(size_t)row * 1024 + col] = (f16)acc[m][n][j];
      }
}

// ---------------------------------------------------------------- scores = HM . H^T (+bias), f32 out
__global__ __launch_bounds__(256) void k_scores(
    const f16* __restrict__ HM, const f16* __restrict__ Hh,
    const float* __restrict__ bias_table, float* __restrict__ scores)
{
  __shared__ __align__(16) f16 sA[2][4096];
  __shared__ __align__(16) f16 sB[2][4096];
  const int tid = threadIdx.x, lane = tid & 63, w = tid >> 6;
  const int hw = blockIdx.x;
  const int wg = (hw & 7) * 162 + (hw >> 3);
  const int b = wg / 81;
  const int rem = wg % 81;
  const int m0 = (rem % 9) * 128, n0 = (rem / 9) * 128;

  const int sr = w * 32 + (lane >> 2);
  const int cb = (((lane & 3) ^ ((lane >> 3) & 3))) * 16;
  const size_t aoff0 = ((size_t)b*1025 + min(m0 + sr,      1024)) * 2048 + cb;
  const size_t aoff1 = ((size_t)b*1025 + min(m0 + sr + 16, 1024)) * 2048 + cb;
  const size_t boff0 = ((size_t)b*1025 + min(n0 + sr,      1024)) * 2048 + cb;
  const size_t boff1 = ((size_t)b*1025 + min(n0 + sr + 16, 1024)) * 2048 + cb;
  const char* Ap = (const char*)HM;
  const char* Bp = (const char*)Hh;

  const int wr = w >> 1, wc = w & 1;
  const int lrow = lane & 15;
  const int fo = (((lane >> 4) ^ ((lane >> 1) & 3))) * 8;

#define STAGE(buf, kb) \
    gld16(&sA[buf][w*1024],       Ap + aoff0 + (kb)); \
    gld16(&sA[buf][w*1024 + 512], Ap + aoff1 + (kb)); \
    gld16(&sB[buf][w*1024],       Bp + boff0 + (kb)); \
    gld16(&sB[buf][w*1024 + 512], Bp + boff1 + (kb));

  f32x4 acc[4][4] = {};
  STAGE(0, 0)
  __syncthreads();
  int cur = 0;
  for (int t = 0; t < 32; ++t){
    if (t < 31){ STAGE(cur ^ 1, (size_t)(t + 1) * 64) }
    f16x8 a[4], bb[4];
    #pragma unroll
    for (int m = 0; m < 4; m++) a[m]  = *(const f16x8*)&sA[cur][(wr*64 + m*16 + lrow)*32 + fo];
    #pragma unroll
    for (int n = 0; n < 4; n++) bb[n] = *(const f16x8*)&sB[cur][(wc*64 + n*16 + lrow)*32 + fo];
    #pragma unroll
    for (int m = 0; m < 4; m++)
      #pragma unroll
      for (int n = 0; n < 4; n++)
        acc[m][n] = MFMA_F16(a[m], bb[n], acc[m][n], 0, 0, 0);
    __syncthreads();
    cur ^= 1;
  }
#undef STAGE
  const int r4 = (lane >> 4) * 4;
  #pragma unroll
  for (int m = 0; m < 4; m++)
    #pragma unroll
    for (int n = 0; n < 4; n++)
      #pragma unroll
      for (int j = 0; j < 4; j++){
        const int q  = m0 + wr*64 + m*16 + r4 + j;
        const int kk = n0 + wc*64 + n*16 + lrow;
        if (q < 1025 && kk < 1025){
          float v = acc[m][n][j];
          if (q > 0 && kk > 0){
            const int i = q - 1, jj = kk - 1;
            const int yi = i >> 5, xi = i & 31;
            const int yj = jj >> 5, xj = jj & 31;
            const int idx = (yi - yj + 31) * 63 + (xi - xj + 31);
            v += bias_table[idx * 16 + b];
          }
          scores[((size_t)b * 1025 + q) * 1028 + kk] = v;
        }
      }
}

// ---------------------------------------------------------------- V = H . Wv^T (fp16 out)
__global__ __launch_bounds__(256) void k_projv(
    const f16* __restrict__ Hh, const f16* __restrict__ Wvh,
    f16* __restrict__ Vh)
{
  __shared__ __align__(16) f16 sA[2][4096];
  __shared__ __align__(16) f16 sB[2][4096];
  const int tid = threadIdx.x, lane = tid & 63, w = tid >> 6;
  const int hw = blockIdx.x;
  const int wg = (hw & 7) * 129 + (hw >> 3);
  const int m0 = (wg >> 3) * 128;
  const int n0 = (wg & 7) * 128;

  const int sr = w * 32 + (lane >> 2);
  const int cb = (((lane & 3) ^ ((lane >> 3) & 3))) * 16;
  const size_t aoff0 = (size_t)min(m0 + sr,      16399) * 2048 + cb;
  const size_t aoff1 = (size_t)min(m0 + sr + 16, 16399) * 2048 + cb;
  const size_t boff0 = (size_t)(n0 + sr)      * 2048 + cb;
  const size_t boff1 = (size_t)(n0 + sr + 16) * 2048 + cb;
  const char* Ap = (const char*)Hh;
  const char* Bp = (const char*)Wvh;

  const int wr = w >> 1, wc = w & 1;
  const int lrow = lane & 15;
  const int fo = (((lane >> 4) ^ ((lane >> 1) & 3))) * 8;

#define STAGE(buf, kb) \
    gld16(&sA[buf][w*1024],       Ap + aoff0 + (kb)); \
    gld16(&sA[buf][w*1024 + 512], Ap + aoff1 + (kb)); \
    gld16(&sB[buf][w*1024],       Bp + boff0 + (kb)); \
    gld16(&sB[buf][w*1024 + 512], Bp + boff1 + (kb));

  f32x4 acc[4][4] = {};
  STAGE(0, 0)
  __syncthreads();
  int cur = 0;
  for (int t = 0; t < 32; ++t){
    if (t < 31){ STAGE(cur ^ 1, (size_t)(t + 1) * 64) }
    f16x8 a[4], bb[4];
    #pragma unroll
    for (int m = 0; m < 4; m++) a[m]  = *(const f16x8*)&sA[cur][(wr*64 + m*16 + lrow)*32 + fo];
    #pragma unroll
    for (int n = 0; n < 4; n++) bb[n] = *(const f16x8*)&sB[cur][(wc*64 + n*16 + lrow)*32 + fo];
    #pragma unroll
    for (int m = 0; m < 4; m++)
      #pragma unroll
      for (int n = 0; n < 4; n++)
        acc[m][n] = MFMA_F16(a[m], bb[n], acc[m][n], 0, 0, 0);
    __syncthreads();
    cur ^= 1;
  }
#undef STAGE
  const int r4 = (lane >> 4) * 4;
  #pragma unroll
  for (int m = 0; m < 4; m++)
    #pragma unroll
    for (int n = 0; n < 4; n++)
      #pragma unroll
      for (int j = 0; j < 4; j++){
        const int row = m0 + wr*64 + m*16 + r4 + j;
        const int col = n0 + wc*64 + n*16 + lrow;
        if (row < 16400) Vh[(size_t)row * 1024 + col] = (f16)acc[m][n][j];
      }
}

// ---------------------------------------------------------------- V transpose  (Vt stride 1056, pad cols zeroed)
__global__ __launch_bounds__(256) void k_transpose_v(const u16* __restrict__ Vh,
                                                     u16* __restrict__ Vt){
  __shared__ u16 T[32][33];
  const int b = blockIdx.z, s0 = blockIdx.x * 32, e0 = blockIdx.y * 32;
  const int tx = threadIdx.x & 31, ty = threadIdx.x >> 5;
  #pragma unroll
  for (int i = 0; i < 4; i++){
    const int s = s0 + ty + i * 8;
    T[ty + i*8][tx] = (s < 1025) ? Vh[((size_t)b * 1025 + s) * 1024 + e0 + tx] : (u16)0;
  }
  __syncthreads();
  #pragma unroll
  for (int i = 0; i < 4; i++){
    const int e = e0 + ty + i * 8;
    const int s = s0 + tx;
    Vt[((size_t)b * 1024 + e) * 1056 + s] = T[tx][ty + i*8];
  }
}

// ---------------------------------------------------------------- softmax  (P fp16, stride 1056, pad zeroed)
__global__ __launch_bounds__(256) void k_softmax(const float* __restrict__ scores,
                                                 f16* __restrict__ P){
  __shared__ float red[4];
  const int tid = threadIdx.x;
  const size_t R = blockIdx.x;
  const float* __restrict__ row = scores + R * 1028;
  f32x4 v = *(const f32x4*)&row[tid * 4];
  const float extra = (tid == 0) ? row[1024] : -1e30f;
  float mx = fmaxf(fmaxf(v[0], v[1]), fmaxf(v[2], v[3]));
  mx = fmaxf(mx, extra);
  #pragma unroll
  for (int off = 32; off >= 1; off >>= 1) mx = fmaxf(mx, __shfl_down(mx, off, 64));
  if ((tid & 63) == 0) red[tid >> 6] = mx;
  __syncthreads();
  mx = fmaxf(fmaxf(red[0], red[1]), fmaxf(red[2], red[3]));
  __syncthreads();
  f32x4 e;
  e[0] = __expf(v[0] - mx); e[1] = __expf(v[1] - mx);
  e[2] = __expf(v[2] - mx); e[3] = __expf(v[3] - mx);
  const float e4 = (tid == 0) ? __expf(extra - mx) : 0.f;
  float s = e[0] + e[1] + e[2] + e[3] + e4;
  #pragma unroll
  for (int off = 32; off >= 1; off >>= 1) s += __shfl_down(s, off, 64);
  if ((tid & 63) == 0) red[tid >> 6] = s;
  __syncthreads();
  s = red[0] + red[1] + red[2] + red[3];
  const float inv = 1.0f / s;
  f16x4 p;
  p[0] = (f16)(e[0] * inv); p[1] = (f16)(e[1] * inv);
  p[2] = (f16)(e[2] * inv); p[3] = (f16)(e[3] * inv);
  *(f16x4*)&P[R * 1056 + tid * 4] = p;
  if (tid < 32){
    P[R * 1056 + 1024 + tid] = (tid == 0) ? (f16)(e4 * inv) : (f16)0.f;
  }
}

// ---------------------------------------------------------------- PV GEMM (fp16, f32 out)
__global__ __launch_bounds__(256) void k_pv(const f16* __restrict__ P,
                                            const f16* __restrict__ Vt,
                                            float* __restrict__ out)
{
  __shared__ __align__(16) f16 sA[2][4096];
  __shared__ __align__(16) f16 sB[2][4096];
  const int tid = threadIdx.x, lane = tid & 63, w = tid >> 6;
  const int hw = blockIdx.x;
  const int wg = (hw & 7) * 144 + (hw >> 3);
  const int b = wg / 72;
  const int rem = wg % 72;
  const int m0 = (rem >> 3) * 128;
  const int n0 = (rem & 7) * 128;

  const int sr = w * 32 + (lane >> 2);
  const int cb = (((lane & 3) ^ ((lane >> 3) & 3))) * 16;
  const size_t aoff0 = ((size_t)b*1025 + min(m0 + sr,      1024)) * 2112 + cb;
  const size_t aoff1 = ((size_t)b*1025 + min(m0 + sr + 16, 1024)) * 2112 + cb;
  const size_t boff0 = ((size_t)b*1024 + n0 + sr)      * 2112 + cb;
  const size_t boff1 = ((size_t)b*1024 + n0 + sr + 16) * 2112 + cb;
  const char* Ap = (const char*)P;
  const char* Bp = (const char*)Vt;

  const int wr = w >> 1, wc = w & 1;
  const int lrow = lane & 15;
  const int fo = (((lane >> 4) ^ ((lane >> 1) & 3))) * 8;

#define STAGE(buf, kb) \
    gld16(&sA[buf][w*1024],       Ap + aoff0 + (kb)); \
    gld16(&sA[buf][w*1024 + 512], Ap + aoff1 + (kb)); \
    gld16(&sB[buf][w*1024],       Bp + boff0 + (kb)); \
    gld16(&sB[buf][w*1024 + 512], Bp + boff1 + (kb));

  f32x4 acc[4][4] = {};
  STAGE(0, 0)
  __syncthreads();
  int cur = 0;
  for (int t = 0; t < 33; ++t){
    if (t < 32){ STAGE(cur ^ 1, (size_t)(t + 1) * 64) }
    f16x8 a[4], bb[4];
    #pragma unroll
    for (int m = 0; m < 4; m++) a[m]  = *(const f16x8*)&sA[cur][(wr*64 + m*16 + lrow)*32 + fo];
    #pragma unroll
    for (int n = 0; n < 4; n++) bb[n] = *(const f16x8*)&sB[cur][(wc*64 + n*16 + lrow)*32 + fo];
    #pragma unroll
    for (int m = 0; m < 4; m++)
      #pragma unroll
      for (int n = 0; n < 4; n++)
        acc[m][n] = MFMA_F16(a[m], bb[n], acc[m][n], 0, 0, 0);
    __syncthreads();
    cur ^= 1;
  }
#undef STAGE
  const int r4 = (lane >> 4) * 4;
  #pragma unroll
  for (int m = 0; m < 4; m++)
    #pragma unroll
    for (int n = 0; n < 4; n++)
      #pragma unroll
      for (int j = 0; j < 4; j++){
        const int q = m0 + wr*64 + m*16 + r4 + j;
        const int e = n0 + wc*64 + n*16 + lrow;
        if (q < 1025){
          out[((size_t)b * 1025 + q) * 1024 + e] = acc[m][n][j];
        }
      }
}

// ---------------------------------------------------------------- launch
extern "C" void kernel_launch(void* const* d_in, const int* in_sizes, int n_in,
                              void* d_out, int out_size, void* d_ws, size_t ws_size,
                              hipStream_t stream)
{
  const float* H          = (const float*)d_in[0];
  const float* Wq         = (const float*)d_in[1];
  const float* Wk         = (const float*)d_in[2];
  const float* Wv         = (const float*)d_in[3];
  const float* bias_table = (const float*)d_in[4];
  float* out = (float*)d_out;
  char* ws = (char*)d_ws;

  // workspace layout (bytes), peak ~176.6 MB:
  //  [0,           33,587,200)  Hh         -> later P [0, 34,636,800) (Hh+Wqt head; both dead)
  //  [33,587,200,  35,684,352)  Wqt
  //  [35,684,352,  37,781,504)  Wkt
  //  [37,781,504,  39,878,656)  Wvh
  //  [39,878,656,  41,975,808)  GT
  //  [41,975,808,  75,563,008)  HM         -> later Vt [41,975,808, 76,578,816) (HM+scores head; both dead)
  //  [75,563,008, 142,999,808)  scores (f32, stride 1028)
  //  [142,999,808,176,587,008)  Vh
  f16* Hh  = (f16*)(ws + 0);
  f16* Wqt = (f16*)(ws + 33587200ull);
  f16* Wkt = (f16*)(ws + 35684352ull);
  f16* Wvh = (f16*)(ws + 37781504ull);
  f16* GT  = (f16*)(ws + 39878656ull);
  f16* HM  = (f16*)(ws + 41975808ull);
  float* scores = (float*)(ws + 75563008ull);
  f16* Vh  = (f16*)(ws + 142999808ull);
  f16* P   = (f16*)(ws + 0);             // over Hh/Wqt (dead after k_projv / k_gt)
  f16* Vt  = (f16*)(ws + 41975808ull);   // over HM (dead after k_scores) + scores head (dead after k_softmax)

  k_split_wt   <<<dim3(32, 32, 3),   256, 0, stream>>>(Wq, Wk, Wv, Wqt, Wkt, Wvh);
  k_prep_h     <<<dim3(16400, 1, 1), 256, 0, stream>>>(H, Hh);
  k_gt         <<<dim3(8, 8, 1),     256, 0, stream>>>(Wkt, Wqt, GT);
  k_ghm        <<<dim3(1032, 1, 1),  256, 0, stream>>>(Hh, GT, HM);
  k_scores     <<<dim3(1296, 1, 1),  256, 0, stream>>>(HM, Hh, bias_table, scores);
  k_projv      <<<dim3(1032, 1, 1),  256, 0, stream>>>(Hh, Wvh, Vh);
  k_softmax    <<<dim3(16400, 1, 1), 256, 0, stream>>>(scores, P);
  k_transpose_v<<<dim3(33, 32, 16),  256, 0, stream>>>((const u16*)Vh, (u16*)Vt);
  k_pv         <<<dim3(1152, 1, 1),  256, 0, stream>>>(P, Vt, out);
}